// Round 2
// baseline (628.576 us; speedup 1.0000x reference)
//
#include <hip/hip_runtime.h>
#include <math.h>

#define NEG_SLOPE 0.2f
#define BN_EPS 1e-5f

__device__ __forceinline__ float lrelu_f(float x){ return x > 0.f ? x : NEG_SLOPE * x; }
__device__ __forceinline__ float elu_f(float x){ return x > 0.f ? x : __expf(x) - 1.f; }

// ---------- CSR build ----------
__global__ void k_count(const int* __restrict__ ei, int E0, int N, int* __restrict__ counts){
    int i = blockIdx.x * blockDim.x + threadIdx.x;
    int tot = E0 + N;
    if (i >= tot) return;
    int dst = (i < E0) ? ei[E0 + i] : (i - E0);   // self-loops appended
    atomicAdd(&counts[dst], 1);
}

__global__ void k_scan(const int* __restrict__ counts, int* __restrict__ row_ptr, int n){
    __shared__ int part[1024];
    int tid = threadIdx.x;
    int chunk = (n + 1023) / 1024;
    int beg = tid * chunk; if (beg > n) beg = n;
    int end = beg + chunk; if (end > n) end = n;
    int s = 0;
    for (int i = beg; i < end; ++i) s += counts[i];
    part[tid] = s;
    __syncthreads();
    for (int off = 1; off < 1024; off <<= 1){
        int v = 0;
        if (tid >= off) v = part[tid - off];
        __syncthreads();
        if (tid >= off) part[tid] += v;
        __syncthreads();
    }
    int run = part[tid] - s;          // exclusive prefix
    for (int i = beg; i < end; ++i){ row_ptr[i] = run; run += counts[i]; }
    if (end == n && beg < n) row_ptr[n] = run;
}

__global__ void k_scatter(const int* __restrict__ ei, int E0, int N,
                          const int* __restrict__ row_ptr, int* __restrict__ cursor,
                          int* __restrict__ csr_src){
    int i = blockIdx.x * blockDim.x + threadIdx.x;
    int tot = E0 + N;
    if (i >= tot) return;
    int src, dst;
    if (i < E0){ src = ei[i]; dst = ei[E0 + i]; } else { src = dst = i - E0; }
    int pos = atomicAdd(&cursor[dst], 1);
    csr_src[row_ptr[dst] + pos] = src;
}

__global__ void k_graph_ptr(const int* __restrict__ batch, int N, int G, int* __restrict__ gp){
    int i = blockIdx.x * blockDim.x + threadIdx.x;
    if (i >= N) return;
    int b = batch[i];
    if (i == 0){ for (int g = 0; g <= b; ++g) gp[g] = 0; }
    else { int pb = batch[i - 1]; for (int g = pb + 1; g <= b; ++g) gp[g] = i; }
    if (i == N - 1){ for (int g = b + 1; g <= G; ++g) gp[g] = N; }
}

// ---------- layer 1 GEMM (IN=5 -> OUT=128, H=4) + attention dots ----------
__global__ void k_gemm1(const float* __restrict__ X, const float* __restrict__ W,
                        const float* __restrict__ atts, const float* __restrict__ attd,
                        float* __restrict__ h, float* __restrict__ as_, float* __restrict__ ad_,
                        int N){
    __shared__ float Wl[5 * 128];
    __shared__ float Xl[2][5];
    int tid = threadIdx.x;
    for (int i = tid; i < 5 * 128; i += 256) Wl[i] = W[i];
    int c = tid & 127, local = tid >> 7;
    float as_c = atts[c], ad_c = attd[c];
    for (long base = (long)blockIdx.x * 2; base < N; base += (long)gridDim.x * 2){
        __syncthreads();
        if (tid < 10){
            long nn = base + tid / 5;
            Xl[tid / 5][tid % 5] = (nn < N) ? X[nn * 5 + tid % 5] : 0.f;
        }
        __syncthreads();
        long node = base + local;
        if (node < N){
            float acc = 0.f;
#pragma unroll
            for (int k = 0; k < 5; ++k) acc += Xl[local][k] * Wl[k * 128 + c];
            float vs = acc * as_c, vd = acc * ad_c;
#pragma unroll
            for (int m = 1; m < 32; m <<= 1){ vs += __shfl_xor(vs, m); vd += __shfl_xor(vd, m); }
            h[node * 128 + c] = acc;
            if ((c & 31) == 0){ as_[node * 4 + (c >> 5)] = vs; ad_[node * 4 + (c >> 5)] = vd; }
        }
    }
}

// ---------- generic GEMM (IN=128 -> OUT, H heads) + attention dots ----------
template<int OUT, int H>
__global__ void k_gemm(const float* __restrict__ X, const float* __restrict__ W,
                       const float* __restrict__ atts, const float* __restrict__ attd,
                       float* __restrict__ h, float* __restrict__ as_, float* __restrict__ ad_,
                       int N){
    constexpr int NPB = 256 / OUT;
    constexpr int GROUP = OUT / H;
    __shared__ float Wl[128 * OUT];
    __shared__ float Xl[NPB * 128];
    int tid = threadIdx.x;
    for (int i = tid; i < 128 * OUT; i += 256) Wl[i] = W[i];
    int c = tid % OUT, local = tid / OUT;
    float as_c = atts[c], ad_c = attd[c];
    for (long base = (long)blockIdx.x * NPB; base < N; base += (long)gridDim.x * NPB){
        __syncthreads();
        for (int i = tid; i < NPB * 128; i += 256){
            long nn = base + i / 128;
            Xl[i] = (nn < N) ? X[nn * 128 + (i & 127)] : 0.f;
        }
        __syncthreads();
        long node = base + local;
        if (node < N){
            float acc = 0.f;
#pragma unroll 16
            for (int k = 0; k < 128; ++k) acc += Xl[local * 128 + k] * Wl[k * OUT + c];
            float vs = acc * as_c, vd = acc * ad_c;
#pragma unroll
            for (int m = 1; m < GROUP; m <<= 1){ vs += __shfl_xor(vs, m); vd += __shfl_xor(vd, m); }
            h[node * OUT + c] = acc;
            if (c % GROUP == 0){ as_[node * H + c / GROUP] = vs; ad_[node * H + c / GROUP] = vd; }
        }
    }
}

// ---------- GAT aggregation: one wave per destination node ----------
template<int C, int H, int ACT>   // ACT: 0 = none, 1 = ELU
__global__ void k_agg(const float* __restrict__ h, const float* __restrict__ as_,
                      const float* __restrict__ ad_, const int* __restrict__ row_ptr,
                      const int* __restrict__ csr_src, const float* __restrict__ bias,
                      float* __restrict__ out, int N){
    constexpr int PER = C / 64;
    constexpr int GROUP = C / H;
    constexpr int RW = (GROUP < 64) ? GROUP : 64;
    int n = blockIdx.x;
    if (n >= N) return;
    int lane = threadIdx.x;
    int hh[PER]; float ad[PER];
#pragma unroll
    for (int j = 0; j < PER; ++j){
        int cj = lane + j * 64;
        hh[j] = cj / GROUP;
        ad[j] = ad_[n * H + hh[j]];
    }
    int beg = row_ptr[n], end = row_ptr[n + 1];
    float m[PER];
#pragma unroll
    for (int j = 0; j < PER; ++j) m[j] = -1e30f;
    // pass 1: per-head max. Each RW-lane reduce group must cover ALL edges:
    // lane iterates e = beg + (lane % RW) with stride RW, evaluating the logit
    // for its OWN head. (Bug in prev round: stride 64 left half the groups
    // with no edges -> m=-1e30 -> exp overflow -> NaN.)
    int lr = lane & (RW - 1);
    for (int e = beg + lr; e < end; e += RW){
        int s = csr_src[e];
#pragma unroll
        for (int j = 0; j < PER; ++j){
            float l = lrelu_f(as_[s * H + hh[j]] + ad[j]);
            m[j] = fmaxf(m[j], l);
        }
    }
#pragma unroll
    for (int j = 0; j < PER; ++j){
#pragma unroll
        for (int mm = 1; mm < RW; mm <<= 1) m[j] = fmaxf(m[j], __shfl_xor(m[j], mm));
    }
    // pass 2: serial over edges, all lanes gather channels
    float acc[PER], dn[PER];
#pragma unroll
    for (int j = 0; j < PER; ++j){ acc[j] = 0.f; dn[j] = 0.f; }
    for (int e = beg; e < end; ++e){
        int s = csr_src[e];
#pragma unroll
        for (int j = 0; j < PER; ++j){
            float l = lrelu_f(as_[s * H + hh[j]] + ad[j]);
            float p = __expf(l - m[j]);
            dn[j] += p;
            acc[j] += p * h[(long)s * C + lane + j * 64];
        }
    }
#pragma unroll
    for (int j = 0; j < PER; ++j){
        int cj = lane + j * 64;
        float v = acc[j] / (dn[j] + 1e-16f) + bias[cj];
        if (ACT == 1) v = elu_f(v);
        out[(long)n * C + cj] = v;
    }
}

// ---------- BatchNorm ----------
__global__ void k_bn_stats(const float* __restrict__ x, int N,
                           float* __restrict__ sums, float* __restrict__ sumsq){
    __shared__ float s1[256], s2[256];
    int tid = threadIdx.x;
    int c = tid & 127, half = tid >> 7;
    float s = 0.f, q = 0.f;
    for (long i = (long)blockIdx.x * 2 + half; i < N; i += (long)gridDim.x * 2){
        float v = x[i * 128 + c]; s += v; q += v * v;
    }
    s1[tid] = s; s2[tid] = q;
    __syncthreads();
    if (tid < 128){
        s += s1[tid + 128]; q += s2[tid + 128];
        atomicAdd(&sums[c], s); atomicAdd(&sumsq[c], q);
    }
}

__global__ void k_bn_apply(float* __restrict__ x, int N, const float* __restrict__ sums,
                           const float* __restrict__ sumsq, const float* __restrict__ g,
                           const float* __restrict__ be){
    long i = (long)blockIdx.x * blockDim.x + threadIdx.x;
    long tot = (long)N * 128;
    if (i >= tot) return;
    int c = (int)(i & 127);
    float mu = sums[c] / N;
    float var = sumsq[c] / N - mu * mu;
    float sc = g[c] * rsqrtf(var + BN_EPS);
    float v = (x[i] - mu) * sc + be[c];
    x[i] = elu_f(v);
}

// ---------- pooling ----------
__global__ void k_pool(const float* __restrict__ x, const int* __restrict__ gp,
                       float* __restrict__ out, int G){
    __shared__ float ssum[256], smax[256];
    int g = blockIdx.x;
    int tid = threadIdx.x;
    int c = tid & 63, sub = tid >> 6;
    int beg = gp[g], end = gp[g + 1];
    float s = 0.f, mx = -1e30f;
    for (int i = beg + sub; i < end; i += 4){
        float v = x[(long)i * 64 + c];
        s += v; mx = fmaxf(mx, v);
    }
    ssum[tid] = s; smax[tid] = mx;
    __syncthreads();
    if (tid < 64){
        for (int k = 1; k < 4; ++k){ s += ssum[tid + 64 * k]; mx = fmaxf(mx, smax[tid + 64 * k]); }
        int cnt = end - beg;
        out[g * 128 + c]      = (cnt > 0) ? s / (float)cnt : 0.f;
        out[g * 128 + 64 + c] = (cnt > 0) ? mx : 0.f;
    }
}

extern "C" void kernel_launch(void* const* d_in, const int* in_sizes, int n_in,
                              void* d_out, int out_size, void* d_ws, size_t ws_size,
                              hipStream_t stream){
    const float* x   = (const float*)d_in[0];
    const int*   ei  = (const int*)d_in[1];
    const int*   bat = (const int*)d_in[2];
    const float* W1  = (const float*)d_in[3];
    const float* a1s = (const float*)d_in[4];
    const float* a1d = (const float*)d_in[5];
    const float* b1  = (const float*)d_in[6];
    const float* g1  = (const float*)d_in[7];
    const float* be1 = (const float*)d_in[8];
    const float* W2  = (const float*)d_in[9];
    const float* a2s = (const float*)d_in[10];
    const float* a2d = (const float*)d_in[11];
    const float* b2  = (const float*)d_in[12];
    const float* g2  = (const float*)d_in[13];
    const float* be2 = (const float*)d_in[14];
    const float* W3  = (const float*)d_in[15];
    const float* a3s = (const float*)d_in[16];
    const float* a3d = (const float*)d_in[17];
    const float* b3  = (const float*)d_in[18];
    float* out = (float*)d_out;

    int N  = in_sizes[2];        // 50000
    int E0 = in_sizes[1] / 2;    // 600000
    int E  = E0 + N;             // + self-loops
    const int G = 64;

    char* ws = (char*)d_ws;
    size_t off = 0;
    auto alloc = [&](size_t bytes) -> char* {
        char* p = ws + off;
        off += (bytes + 255) & ~(size_t)255;
        return p;
    };
    int*   counts  = (int*)alloc((size_t)N * 4);
    int*   cursor  = (int*)alloc((size_t)N * 4);
    int*   row_ptr = (int*)alloc((size_t)(N + 1) * 4);
    int*   csr     = (int*)alloc((size_t)E * 4);
    int*   gp      = (int*)alloc((size_t)(G + 1) * 4);
    float* as_buf  = (float*)alloc((size_t)N * 4 * 4);
    float* ad_buf  = (float*)alloc((size_t)N * 4 * 4);
    float* sums    = (float*)alloc(128 * 4);
    float* sumsq   = (float*)alloc(128 * 4);
    float* hbuf    = (float*)alloc((size_t)N * 128 * 4);
    float* xcur    = (float*)alloc((size_t)N * 128 * 4);

    hipMemsetAsync(counts, 0, (size_t)N * 4, stream);
    hipMemsetAsync(cursor, 0, (size_t)N * 4, stream);
    k_count<<<(E + 255) / 256, 256, 0, stream>>>(ei, E0, N, counts);
    k_scan<<<1, 1024, 0, stream>>>(counts, row_ptr, N);
    k_scatter<<<(E + 255) / 256, 256, 0, stream>>>(ei, E0, N, row_ptr, cursor, csr);
    k_graph_ptr<<<(N + 255) / 256, 256, 0, stream>>>(bat, N, G, gp);

    // layer 1: 5 -> 128 (4 heads), BN + ELU
    k_gemm1<<<1024, 256, 0, stream>>>(x, W1, a1s, a1d, hbuf, as_buf, ad_buf, N);
    k_agg<128, 4, 0><<<N, 64, 0, stream>>>(hbuf, as_buf, ad_buf, row_ptr, csr, b1, xcur, N);
    hipMemsetAsync(sums, 0, 128 * 4, stream);
    hipMemsetAsync(sumsq, 0, 128 * 4, stream);
    k_bn_stats<<<512, 256, 0, stream>>>(xcur, N, sums, sumsq);
    k_bn_apply<<<(int)(((long)N * 128 + 255) / 256), 256, 0, stream>>>(xcur, N, sums, sumsq, g1, be1);

    // layer 2: 128 -> 128 (4 heads), BN + ELU
    k_gemm<128, 4><<<2048, 256, 0, stream>>>(xcur, W2, a2s, a2d, hbuf, as_buf, ad_buf, N);
    k_agg<128, 4, 0><<<N, 64, 0, stream>>>(hbuf, as_buf, ad_buf, row_ptr, csr, b2, xcur, N);
    hipMemsetAsync(sums, 0, 128 * 4, stream);
    hipMemsetAsync(sumsq, 0, 128 * 4, stream);
    k_bn_stats<<<512, 256, 0, stream>>>(xcur, N, sums, sumsq);
    k_bn_apply<<<(int)(((long)N * 128 + 255) / 256), 256, 0, stream>>>(xcur, N, sums, sumsq, g2, be2);

    // layer 3: 128 -> 64 (1 head), ELU fused in agg
    k_gemm<64, 1><<<2048, 256, 0, stream>>>(xcur, W3, a3s, a3d, hbuf, as_buf, ad_buf, N);
    k_agg<64, 1, 1><<<N, 64, 0, stream>>>(hbuf, as_buf, ad_buf, row_ptr, csr, b3, xcur, N);

    // pooling
    k_pool<<<G, 256, 0, stream>>>(xcur, gp, out, G);
}

// Round 3
// 510.147 us; speedup vs baseline: 1.2321x; 1.2321x over previous
//
#include <hip/hip_runtime.h>
#include <math.h>

#define NEG_SLOPE 0.2f
#define BN_EPS 1e-5f

__device__ __forceinline__ float lrelu_f(float x){ return x > 0.f ? x : NEG_SLOPE * x; }
__device__ __forceinline__ float elu_f(float x){ return x > 0.f ? x : __expf(x) - 1.f; }

// ---------- CSR build ----------
__global__ void k_count(const int* __restrict__ ei, int E0, int N, int* __restrict__ counts){
    int i = blockIdx.x * blockDim.x + threadIdx.x;
    int tot = E0 + N;
    if (i >= tot) return;
    int dst = (i < E0) ? ei[E0 + i] : (i - E0);   // self-loops appended
    atomicAdd(&counts[dst], 1);
}

__global__ void k_scan(const int* __restrict__ counts, int* __restrict__ row_ptr, int n){
    __shared__ int part[1024];
    int tid = threadIdx.x;
    int chunk = (n + 1023) / 1024;
    int beg = tid * chunk; if (beg > n) beg = n;
    int end = beg + chunk; if (end > n) end = n;
    int s = 0;
    for (int i = beg; i < end; ++i) s += counts[i];
    part[tid] = s;
    __syncthreads();
    for (int off = 1; off < 1024; off <<= 1){
        int v = 0;
        if (tid >= off) v = part[tid - off];
        __syncthreads();
        if (tid >= off) part[tid] += v;
        __syncthreads();
    }
    int run = part[tid] - s;          // exclusive prefix
    for (int i = beg; i < end; ++i){ row_ptr[i] = run; run += counts[i]; }
    if (end == n && beg < n) row_ptr[n] = run;
}

__global__ void k_scatter(const int* __restrict__ ei, int E0, int N,
                          const int* __restrict__ row_ptr, int* __restrict__ cursor,
                          int* __restrict__ csr_src){
    int i = blockIdx.x * blockDim.x + threadIdx.x;
    int tot = E0 + N;
    if (i >= tot) return;
    int src, dst;
    if (i < E0){ src = ei[i]; dst = ei[E0 + i]; } else { src = dst = i - E0; }
    int pos = atomicAdd(&cursor[dst], 1);
    csr_src[row_ptr[dst] + pos] = src;
}

__global__ void k_graph_ptr(const int* __restrict__ batch, int N, int G, int* __restrict__ gp){
    int i = blockIdx.x * blockDim.x + threadIdx.x;
    if (i >= N) return;
    int b = batch[i];
    if (i == 0){ for (int g = 0; g <= b; ++g) gp[g] = 0; }
    else { int pb = batch[i - 1]; for (int g = pb + 1; g <= b; ++g) gp[g] = i; }
    if (i == N - 1){ for (int g = b + 1; g <= G; ++g) gp[g] = N; }
}

// ---------- layer 1 GEMM (IN=5 -> OUT=128, H=4) + attention dots ----------
__global__ void k_gemm1(const float* __restrict__ X, const float* __restrict__ W,
                        const float* __restrict__ atts, const float* __restrict__ attd,
                        float* __restrict__ h, float* __restrict__ as_, float* __restrict__ ad_,
                        int N){
    __shared__ float Wl[5 * 128];
    int tid = threadIdx.x;
    for (int i = tid; i < 5 * 128; i += 256) Wl[i] = W[i];
    __syncthreads();
    int c = tid & 127, local = tid >> 7;
    float as_c = atts[c], ad_c = attd[c];
    long node = (long)blockIdx.x * 2 + local;
    if (node >= N) return;
    float x0 = X[node * 5 + 0], x1 = X[node * 5 + 1], x2 = X[node * 5 + 2],
          x3 = X[node * 5 + 3], x4 = X[node * 5 + 4];
    float acc = x0 * Wl[c] + x1 * Wl[128 + c] + x2 * Wl[256 + c] +
                x3 * Wl[384 + c] + x4 * Wl[512 + c];
    float vs = acc * as_c, vd = acc * ad_c;
#pragma unroll
    for (int m = 1; m < 32; m <<= 1){ vs += __shfl_xor(vs, m); vd += __shfl_xor(vd, m); }
    h[node * 128 + c] = acc;
    if ((c & 31) == 0){ as_[node * 4 + (c >> 5)] = vs; ad_[node * 4 + (c >> 5)] = vd; }
}

// ---------- register-tiled GEMM (IN=128 -> OUT, H heads), optional fused BN+ELU on input ----------
template<int OUT, int H, bool BN>
__launch_bounds__(256)
__global__ void k_gemm_rt(const float* __restrict__ X, const float* __restrict__ W,
                          const float* __restrict__ atts, const float* __restrict__ attd,
                          const float* __restrict__ coefs, const float* __restrict__ coefb,
                          float* __restrict__ h, float* __restrict__ as_, float* __restrict__ ad_,
                          int N){
    constexpr int NCX = OUT / 4;        // threads along cols (32 or 16)
    constexpr int NNY = 256 / NCX;      // node groups (8 or 16)
    constexpr int TN  = NNY * 4;        // node tile (32 or 64)
    constexpr int KK  = 32;             // K chunk
    constexpr int XST = TN + 4;         // padded XT row stride (36 or 68 -> 16B-multiple rows)
    __shared__ __align__(16) float Wl[KK * OUT];
    __shared__ __align__(16) float XT[KK * XST];
    int tid = threadIdx.x;
    int cx = tid % NCX, ny = tid / NCX;
    long base = (long)blockIdx.x * TN;
    float a_s[4], a_d[4];
#pragma unroll
    for (int j = 0; j < 4; ++j){ a_s[j] = atts[4 * cx + j]; a_d[j] = attd[4 * cx + j]; }
    float acc[4][4];
#pragma unroll
    for (int i = 0; i < 4; ++i)
#pragma unroll
        for (int j = 0; j < 4; ++j) acc[i][j] = 0.f;

    for (int kk = 0; kk < 128; kk += KK){
        __syncthreads();
        // stage W chunk (contiguous copy)
        for (int i = tid; i < KK * OUT; i += 256) Wl[i] = W[kk * OUT + i];
        // stage X chunk transposed, with optional BN+ELU
        for (int i = tid; i < TN * KK; i += 256){
            int n = i >> 5, r = i & 31;
            long nn = base + n;
            float v = 0.f;
            if (nn < N){
                v = X[nn * 128 + kk + r];
                if (BN) v = elu_f(fmaf(v, coefs[kk + r], coefb[kk + r]));
            }
            XT[r * XST + n] = v;
        }
        __syncthreads();
#pragma unroll
        for (int k = 0; k < KK; ++k){
            const float4 xv = *(const float4*)&XT[k * XST + 4 * ny];
            const float4 wv = *(const float4*)&Wl[k * OUT + 4 * cx];
            acc[0][0] += xv.x * wv.x; acc[0][1] += xv.x * wv.y; acc[0][2] += xv.x * wv.z; acc[0][3] += xv.x * wv.w;
            acc[1][0] += xv.y * wv.x; acc[1][1] += xv.y * wv.y; acc[1][2] += xv.y * wv.z; acc[1][3] += xv.y * wv.w;
            acc[2][0] += xv.z * wv.x; acc[2][1] += xv.z * wv.y; acc[2][2] += xv.z * wv.z; acc[2][3] += xv.z * wv.w;
            acc[3][0] += xv.w * wv.x; acc[3][1] += xv.w * wv.y; acc[3][2] += xv.w * wv.z; acc[3][3] += xv.w * wv.w;
        }
    }
    long n0 = base + 4 * ny;
    // write h (float4 per node)
#pragma unroll
    for (int i = 0; i < 4; ++i){
        long n = n0 + i;
        if (n < N){
            float4 o; o.x = acc[i][0]; o.y = acc[i][1]; o.z = acc[i][2]; o.w = acc[i][3];
            *(float4*)&h[n * OUT + 4 * cx] = o;
        }
    }
    // attention dot partials + cross-lane reduce within each head
    float ps[4], pd[4];
#pragma unroll
    for (int i = 0; i < 4; ++i){
        ps[i] = acc[i][0] * a_s[0] + acc[i][1] * a_s[1] + acc[i][2] * a_s[2] + acc[i][3] * a_s[3];
        pd[i] = acc[i][0] * a_d[0] + acc[i][1] * a_d[1] + acc[i][2] * a_d[2] + acc[i][3] * a_d[3];
    }
    constexpr int RED = NCX / H;   // lanes per head (8 or 16); cx == lane % NCX so xor<RED stays in-head
#pragma unroll
    for (int m = 1; m < RED; m <<= 1){
#pragma unroll
        for (int i = 0; i < 4; ++i){ ps[i] += __shfl_xor(ps[i], m); pd[i] += __shfl_xor(pd[i], m); }
    }
    if (cx % RED == 0){
        int hh = cx / RED;
#pragma unroll
        for (int i = 0; i < 4; ++i){
            long n = n0 + i;
            if (n < N){ as_[n * H + hh] = ps[i]; ad_[n * H + hh] = pd[i]; }
        }
    }
}

// ---------- GAT aggregation: one wave per destination node, single pass (no max shift) ----------
// Softmax is shift-invariant; logits are O(+-10) so fp32 exp cannot overflow, and the
// self-loop guarantees denom > 0. Matches reference to fp rounding.
template<int C, int H, int ACT>   // ACT: 0 = none, 1 = ELU
__global__ void k_agg(const float* __restrict__ h, const float* __restrict__ as_,
                      const float* __restrict__ ad_, const int* __restrict__ row_ptr,
                      const int* __restrict__ csr_src, const float* __restrict__ bias,
                      float* __restrict__ out, int N){
    constexpr int CPL = C / 64;         // channels per lane (2 for C=128, 1 for C=64)
    constexpr int GROUP = C / H;
    int n = blockIdx.x;
    if (n >= N) return;
    int lane = threadIdx.x;
    int hh = (CPL * lane) / GROUP;      // same head for both packed channels (CPL=2, GROUP=32)
    float ad = ad_[n * H + hh];
    int beg = row_ptr[n], end = row_ptr[n + 1];
    float accx = 0.f, accy = 0.f, dn = 0.f;
    for (int e = beg; e < end; ++e){
        int s = csr_src[e];
        float l = lrelu_f(as_[s * H + hh] + ad);
        float p = __expf(l);
        dn += p;
        if (CPL == 2){
            float2 hv = *(const float2*)&h[(long)s * C + 2 * lane];
            accx += p * hv.x; accy += p * hv.y;
        } else {
            accx += p * h[(long)s * C + lane];
        }
    }
    float inv = 1.f / dn;
    if (CPL == 2){
        float vx = accx * inv + bias[2 * lane];
        float vy = accy * inv + bias[2 * lane + 1];
        if (ACT == 1){ vx = elu_f(vx); vy = elu_f(vy); }
        float2 o; o.x = vx; o.y = vy;
        *(float2*)&out[(long)n * C + 2 * lane] = o;
    } else {
        float v = accx * inv + bias[lane];
        if (ACT == 1) v = elu_f(v);
        out[(long)n * C + lane] = v;
    }
}

// ---------- BatchNorm stats + coefficient precompute ----------
__global__ void k_bn_stats(const float* __restrict__ x, int N,
                           float* __restrict__ sums, float* __restrict__ sumsq){
    __shared__ float s1[256], s2[256];
    int tid = threadIdx.x;
    int c = tid & 127, half = tid >> 7;
    float s = 0.f, q = 0.f;
    for (long i = (long)blockIdx.x * 2 + half; i < N; i += (long)gridDim.x * 2){
        float v = x[i * 128 + c]; s += v; q += v * v;
    }
    s1[tid] = s; s2[tid] = q;
    __syncthreads();
    if (tid < 128){
        s += s1[tid + 128]; q += s2[tid + 128];
        atomicAdd(&sums[c], s); atomicAdd(&sumsq[c], q);
    }
}

__global__ void k_bn_coef(const float* __restrict__ sums, const float* __restrict__ sumsq,
                          const float* __restrict__ g, const float* __restrict__ be,
                          float invN, float* __restrict__ cs, float* __restrict__ cb){
    int c = threadIdx.x;   // 128 threads
    float mu = sums[c] * invN;
    float var = sumsq[c] * invN - mu * mu;
    float sc = g[c] * rsqrtf(var + BN_EPS);
    cs[c] = sc;
    cb[c] = be[c] - mu * sc;
}

// ---------- pooling ----------
__global__ void k_pool(const float* __restrict__ x, const int* __restrict__ gp,
                       float* __restrict__ out, int G){
    __shared__ float ssum[256], smax[256];
    int g = blockIdx.x;
    int tid = threadIdx.x;
    int c = tid & 63, sub = tid >> 6;
    int beg = gp[g], end = gp[g + 1];
    float s = 0.f, mx = -1e30f;
    for (int i = beg + sub; i < end; i += 4){
        float v = x[(long)i * 64 + c];
        s += v; mx = fmaxf(mx, v);
    }
    ssum[tid] = s; smax[tid] = mx;
    __syncthreads();
    if (tid < 64){
        for (int k = 1; k < 4; ++k){ s += ssum[tid + 64 * k]; mx = fmaxf(mx, smax[tid + 64 * k]); }
        int cnt = end - beg;
        out[g * 128 + c]      = (cnt > 0) ? s / (float)cnt : 0.f;
        out[g * 128 + 64 + c] = (cnt > 0) ? mx : 0.f;
    }
}

extern "C" void kernel_launch(void* const* d_in, const int* in_sizes, int n_in,
                              void* d_out, int out_size, void* d_ws, size_t ws_size,
                              hipStream_t stream){
    const float* x   = (const float*)d_in[0];
    const int*   ei  = (const int*)d_in[1];
    const int*   bat = (const int*)d_in[2];
    const float* W1  = (const float*)d_in[3];
    const float* a1s = (const float*)d_in[4];
    const float* a1d = (const float*)d_in[5];
    const float* b1  = (const float*)d_in[6];
    const float* g1  = (const float*)d_in[7];
    const float* be1 = (const float*)d_in[8];
    const float* W2  = (const float*)d_in[9];
    const float* a2s = (const float*)d_in[10];
    const float* a2d = (const float*)d_in[11];
    const float* b2  = (const float*)d_in[12];
    const float* g2  = (const float*)d_in[13];
    const float* be2 = (const float*)d_in[14];
    const float* W3  = (const float*)d_in[15];
    const float* a3s = (const float*)d_in[16];
    const float* a3d = (const float*)d_in[17];
    const float* b3  = (const float*)d_in[18];
    float* out = (float*)d_out;

    int N  = in_sizes[2];        // 50000
    int E0 = in_sizes[1] / 2;    // 600000
    int E  = E0 + N;             // + self-loops
    const int G = 64;

    char* ws = (char*)d_ws;
    size_t off = 0;
    auto alloc = [&](size_t bytes) -> char* {
        char* p = ws + off;
        off += (bytes + 255) & ~(size_t)255;
        return p;
    };
    int*   counts  = (int*)alloc((size_t)N * 4);
    int*   cursor  = (int*)alloc((size_t)N * 4);
    int*   row_ptr = (int*)alloc((size_t)(N + 1) * 4);
    int*   csr     = (int*)alloc((size_t)E * 4);
    int*   gp      = (int*)alloc((size_t)(G + 1) * 4);
    float* as_buf  = (float*)alloc((size_t)N * 4 * 4);
    float* ad_buf  = (float*)alloc((size_t)N * 4 * 4);
    float* sums    = (float*)alloc(128 * 4);
    float* sumsq   = (float*)alloc(128 * 4);
    float* coefs   = (float*)alloc(128 * 4);
    float* coefb   = (float*)alloc(128 * 4);
    float* hbuf    = (float*)alloc((size_t)N * 128 * 4);
    float* xcur    = (float*)alloc((size_t)N * 128 * 4);

    hipMemsetAsync(counts, 0, (size_t)N * 4, stream);
    hipMemsetAsync(cursor, 0, (size_t)N * 4, stream);
    k_count<<<(E + 255) / 256, 256, 0, stream>>>(ei, E0, N, counts);
    k_scan<<<1, 1024, 0, stream>>>(counts, row_ptr, N);
    k_scatter<<<(E + 255) / 256, 256, 0, stream>>>(ei, E0, N, row_ptr, cursor, csr);
    k_graph_ptr<<<(N + 255) / 256, 256, 0, stream>>>(bat, N, G, gp);

    // layer 1: 5 -> 128 (4 heads); agg writes raw (bias added), BN folded into gemm2 staging
    k_gemm1<<<(N + 1) / 2, 256, 0, stream>>>(x, W1, a1s, a1d, hbuf, as_buf, ad_buf, N);
    k_agg<128, 4, 0><<<N, 64, 0, stream>>>(hbuf, as_buf, ad_buf, row_ptr, csr, b1, xcur, N);
    hipMemsetAsync(sums, 0, 128 * 4, stream);
    hipMemsetAsync(sumsq, 0, 128 * 4, stream);
    k_bn_stats<<<512, 256, 0, stream>>>(xcur, N, sums, sumsq);
    k_bn_coef<<<1, 128, 0, stream>>>(sums, sumsq, g1, be1, 1.f / N, coefs, coefb);

    // layer 2: 128 -> 128 (4 heads), BN1+ELU fused into X staging
    k_gemm_rt<128, 4, true><<<(N + 31) / 32, 256, 0, stream>>>(
        xcur, W2, a2s, a2d, coefs, coefb, hbuf, as_buf, ad_buf, N);
    k_agg<128, 4, 0><<<N, 64, 0, stream>>>(hbuf, as_buf, ad_buf, row_ptr, csr, b2, xcur, N);
    hipMemsetAsync(sums, 0, 128 * 4, stream);
    hipMemsetAsync(sumsq, 0, 128 * 4, stream);
    k_bn_stats<<<512, 256, 0, stream>>>(xcur, N, sums, sumsq);
    k_bn_coef<<<1, 128, 0, stream>>>(sums, sumsq, g2, be2, 1.f / N, coefs, coefb);

    // layer 3: 128 -> 64 (1 head), BN2+ELU fused into X staging, ELU fused in agg
    k_gemm_rt<64, 1, true><<<(N + 63) / 64, 256, 0, stream>>>(
        xcur, W3, a3s, a3d, coefs, coefb, hbuf, as_buf, ad_buf, N);
    k_agg<64, 1, 1><<<N, 64, 0, stream>>>(hbuf, as_buf, ad_buf, row_ptr, csr, b3, xcur, N);

    // pooling
    k_pool<<<G, 256, 0, stream>>>(xcur, gp, out, G);
}

// Round 4
// 431.004 us; speedup vs baseline: 1.4584x; 1.1836x over previous
//
#include <hip/hip_runtime.h>
#include <math.h>

#define NEG_SLOPE 0.2f
#define BN_EPS 1e-5f

__device__ __forceinline__ float lrelu_f(float x){ return x > 0.f ? x : NEG_SLOPE * x; }
__device__ __forceinline__ float elu_f(float x){ return x > 0.f ? x : __expf(x) - 1.f; }

// ---------- CSR build ----------
__global__ void k_count(const int* __restrict__ ei, int E0, int N, int* __restrict__ counts){
    int i = blockIdx.x * blockDim.x + threadIdx.x;
    int tot = E0 + N;
    if (i >= tot) return;
    int dst = (i < E0) ? ei[E0 + i] : (i - E0);   // self-loops appended
    atomicAdd(&counts[dst], 1);
}

// ---------- parallel 3-phase exclusive scan over counts[n] -> row_ptr[n+1] ----------
__global__ void k_scan_part(const int* __restrict__ counts, int n, int* __restrict__ part){
    __shared__ int sh[256];
    int tid = threadIdx.x;
    int i = blockIdx.x * 256 + tid;
    int v = (i < n) ? counts[i] : 0;
    sh[tid] = v;
    __syncthreads();
    for (int o = 128; o > 0; o >>= 1){
        if (tid < o) sh[tid] += sh[tid + o];
        __syncthreads();
    }
    if (tid == 0) part[blockIdx.x] = sh[0];
}

__global__ void k_scan_top(int* __restrict__ part, int P, int n, int* __restrict__ row_ptr){
    __shared__ int sh[256];
    int tid = threadIdx.x;
    int v = (tid < P) ? part[tid] : 0;
    sh[tid] = v;
    __syncthreads();
    for (int o = 1; o < 256; o <<= 1){
        int t = (tid >= o) ? sh[tid - o] : 0;
        __syncthreads();
        sh[tid] += t;
        __syncthreads();
    }
    if (tid < P) part[tid] = sh[tid] - v;       // exclusive block offsets
    if (tid == 0) row_ptr[n] = sh[255];         // total = E
}

__global__ void k_scan_write(const int* __restrict__ counts, const int* __restrict__ part,
                             int n, int* __restrict__ row_ptr){
    __shared__ int sh[256];
    int tid = threadIdx.x;
    int i = blockIdx.x * 256 + tid;
    int v = (i < n) ? counts[i] : 0;
    sh[tid] = v;
    __syncthreads();
    for (int o = 1; o < 256; o <<= 1){
        int t = (tid >= o) ? sh[tid - o] : 0;
        __syncthreads();
        sh[tid] += t;
        __syncthreads();
    }
    if (i < n) row_ptr[i] = part[blockIdx.x] + sh[tid] - v;
}

__global__ void k_scatter(const int* __restrict__ ei, int E0, int N,
                          const int* __restrict__ row_ptr, int* __restrict__ cursor,
                          int* __restrict__ csr_src){
    int i = blockIdx.x * blockDim.x + threadIdx.x;
    int tot = E0 + N;
    if (i >= tot) return;
    int src, dst;
    if (i < E0){ src = ei[i]; dst = ei[E0 + i]; } else { src = dst = i - E0; }
    int pos = atomicAdd(&cursor[dst], 1);
    csr_src[row_ptr[dst] + pos] = src;
}

__global__ void k_graph_ptr(const int* __restrict__ batch, int N, int G, int* __restrict__ gp){
    int i = blockIdx.x * blockDim.x + threadIdx.x;
    if (i >= N) return;
    int b = batch[i];
    if (i == 0){ for (int g = 0; g <= b; ++g) gp[g] = 0; }
    else { int pb = batch[i - 1]; for (int g = pb + 1; g <= b; ++g) gp[g] = i; }
    if (i == N - 1){ for (int g = b + 1; g <= G; ++g) gp[g] = N; }
}

// ---------- layer 1 GEMM (IN=5 -> OUT=128, H=4) + attention dots ----------
__global__ void k_gemm1(const float* __restrict__ X, const float* __restrict__ W,
                        const float* __restrict__ atts, const float* __restrict__ attd,
                        float* __restrict__ h, float* __restrict__ as_, float* __restrict__ ad_,
                        int N){
    __shared__ float Wl[5 * 128];
    int tid = threadIdx.x;
    for (int i = tid; i < 5 * 128; i += 256) Wl[i] = W[i];
    __syncthreads();
    int c = tid & 127, local = tid >> 7;
    float as_c = atts[c], ad_c = attd[c];
    for (long node = (long)blockIdx.x * 2 + local; node < N; node += (long)gridDim.x * 2){
        float x0 = X[node * 5 + 0], x1 = X[node * 5 + 1], x2 = X[node * 5 + 2],
              x3 = X[node * 5 + 3], x4 = X[node * 5 + 4];
        float acc = x0 * Wl[c] + x1 * Wl[128 + c] + x2 * Wl[256 + c] +
                    x3 * Wl[384 + c] + x4 * Wl[512 + c];
        float vs = acc * as_c, vd = acc * ad_c;
#pragma unroll
        for (int m = 1; m < 32; m <<= 1){ vs += __shfl_xor(vs, m); vd += __shfl_xor(vd, m); }
        h[node * 128 + c] = acc;
        if ((c & 31) == 0){ as_[node * 4 + (c >> 5)] = vs; ad_[node * 4 + (c >> 5)] = vd; }
    }
}

// ---------- register-tiled GEMM (IN=128 -> OUT, H heads), optional fused BN+ELU on input ----------
template<int OUT, int H, bool BN>
__launch_bounds__(256)
__global__ void k_gemm_rt(const float* __restrict__ X, const float* __restrict__ W,
                          const float* __restrict__ atts, const float* __restrict__ attd,
                          const float* __restrict__ coefs, const float* __restrict__ coefb,
                          float* __restrict__ h, float* __restrict__ as_, float* __restrict__ ad_,
                          int N){
    constexpr int NCX = OUT / 4;        // threads along cols (32 or 16)
    constexpr int NNY = 256 / NCX;      // node groups (8 or 16)
    constexpr int TN  = NNY * 4;        // node tile (32 or 64)
    constexpr int KK  = 32;             // K chunk
    constexpr int XST = TN + 4;         // padded XT row stride
    __shared__ __align__(16) float Wl[KK * OUT];
    __shared__ __align__(16) float XT[KK * XST];
    int tid = threadIdx.x;
    int cx = tid % NCX, ny = tid / NCX;
    long base = (long)blockIdx.x * TN;
    float a_s[4], a_d[4];
#pragma unroll
    for (int j = 0; j < 4; ++j){ a_s[j] = atts[4 * cx + j]; a_d[j] = attd[4 * cx + j]; }
    float acc[4][4];
#pragma unroll
    for (int i = 0; i < 4; ++i)
#pragma unroll
        for (int j = 0; j < 4; ++j) acc[i][j] = 0.f;

    for (int kk = 0; kk < 128; kk += KK){
        __syncthreads();
        for (int i = tid; i < KK * OUT; i += 256) Wl[i] = W[kk * OUT + i];
        for (int i = tid; i < TN * KK; i += 256){
            int n = i >> 5, r = i & 31;
            long nn = base + n;
            float v = 0.f;
            if (nn < N){
                v = X[nn * 128 + kk + r];
                if (BN) v = elu_f(fmaf(v, coefs[kk + r], coefb[kk + r]));
            }
            XT[r * XST + n] = v;
        }
        __syncthreads();
#pragma unroll
        for (int k = 0; k < KK; ++k){
            const float4 xv = *(const float4*)&XT[k * XST + 4 * ny];
            const float4 wv = *(const float4*)&Wl[k * OUT + 4 * cx];
            acc[0][0] += xv.x * wv.x; acc[0][1] += xv.x * wv.y; acc[0][2] += xv.x * wv.z; acc[0][3] += xv.x * wv.w;
            acc[1][0] += xv.y * wv.x; acc[1][1] += xv.y * wv.y; acc[1][2] += xv.y * wv.z; acc[1][3] += xv.y * wv.w;
            acc[2][0] += xv.z * wv.x; acc[2][1] += xv.z * wv.y; acc[2][2] += xv.z * wv.z; acc[2][3] += xv.z * wv.w;
            acc[3][0] += xv.w * wv.x; acc[3][1] += xv.w * wv.y; acc[3][2] += xv.w * wv.z; acc[3][3] += xv.w * wv.w;
        }
    }
    long n0 = base + 4 * ny;
#pragma unroll
    for (int i = 0; i < 4; ++i){
        long n = n0 + i;
        if (n < N){
            float4 o; o.x = acc[i][0]; o.y = acc[i][1]; o.z = acc[i][2]; o.w = acc[i][3];
            *(float4*)&h[n * OUT + 4 * cx] = o;
        }
    }
    float ps[4], pd[4];
#pragma unroll
    for (int i = 0; i < 4; ++i){
        ps[i] = acc[i][0] * a_s[0] + acc[i][1] * a_s[1] + acc[i][2] * a_s[2] + acc[i][3] * a_s[3];
        pd[i] = acc[i][0] * a_d[0] + acc[i][1] * a_d[1] + acc[i][2] * a_d[2] + acc[i][3] * a_d[3];
    }
    constexpr int RED = NCX / H;   // lanes per head; cx == lane % NCX so xor<RED stays in-head
#pragma unroll
    for (int m = 1; m < RED; m <<= 1){
#pragma unroll
        for (int i = 0; i < 4; ++i){ ps[i] += __shfl_xor(ps[i], m); pd[i] += __shfl_xor(pd[i], m); }
    }
    if (cx % RED == 0){
        int hh = cx / RED;
#pragma unroll
        for (int i = 0; i < 4; ++i){
            long n = n0 + i;
            if (n < N){ as_[n * H + hh] = ps[i]; ad_[n * H + hh] = pd[i]; }
        }
    }
}

// ---------- GAT aggregation: one wave per destination node, single pass (no max shift) ----------
template<int C, int H, int ACT>   // ACT: 0 = none, 1 = ELU
__global__ void k_agg(const float* __restrict__ h, const float* __restrict__ as_,
                      const float* __restrict__ ad_, const int* __restrict__ row_ptr,
                      const int* __restrict__ csr_src, const float* __restrict__ bias,
                      float* __restrict__ out, int N){
    constexpr int CPL = C / 64;         // channels per lane
    constexpr int GROUP = C / H;
    int n = blockIdx.x;
    if (n >= N) return;
    int lane = threadIdx.x;
    int hh = (CPL * lane) / GROUP;
    float ad = ad_[n * H + hh];
    int beg = row_ptr[n], end = row_ptr[n + 1];
    float accx = 0.f, accy = 0.f, dn = 0.f;
    for (int e = beg; e < end; ++e){
        int s = csr_src[e];
        float l = lrelu_f(as_[s * H + hh] + ad);
        float p = __expf(l);
        dn += p;
        if (CPL == 2){
            float2 hv = *(const float2*)&h[(long)s * C + 2 * lane];
            accx += p * hv.x; accy += p * hv.y;
        } else {
            accx += p * h[(long)s * C + lane];
        }
    }
    float inv = 1.f / dn;
    if (CPL == 2){
        float vx = accx * inv + bias[2 * lane];
        float vy = accy * inv + bias[2 * lane + 1];
        if (ACT == 1){ vx = elu_f(vx); vy = elu_f(vy); }
        float2 o; o.x = vx; o.y = vy;
        *(float2*)&out[(long)n * C + 2 * lane] = o;
    } else {
        float v = accx * inv + bias[lane];
        if (ACT == 1) v = elu_f(v);
        out[(long)n * C + lane] = v;
    }
}

// ---------- BatchNorm stats + coefficient precompute ----------
__global__ void k_bn_stats(const float* __restrict__ x, int N,
                           float* __restrict__ sums, float* __restrict__ sumsq){
    __shared__ float s1[256], s2[256];
    int tid = threadIdx.x;
    int c = tid & 127, half = tid >> 7;
    float s = 0.f, q = 0.f;
    for (long i = (long)blockIdx.x * 2 + half; i < N; i += (long)gridDim.x * 2){
        float v = x[i * 128 + c]; s += v; q += v * v;
    }
    s1[tid] = s; s2[tid] = q;
    __syncthreads();
    if (tid < 128){
        s += s1[tid + 128]; q += s2[tid + 128];
        atomicAdd(&sums[c], s); atomicAdd(&sumsq[c], q);
    }
}

__global__ void k_bn_coef(const float* __restrict__ sums, const float* __restrict__ sumsq,
                          const float* __restrict__ g, const float* __restrict__ be,
                          float invN, float* __restrict__ cs, float* __restrict__ cb){
    int c = threadIdx.x;   // 128 threads
    float mu = sums[c] * invN;
    float var = sumsq[c] * invN - mu * mu;
    float sc = g[c] * rsqrtf(var + BN_EPS);
    cs[c] = sc;
    cb[c] = be[c] - mu * sc;
}

// ---------- pooling ----------
__global__ void k_pool(const float* __restrict__ x, const int* __restrict__ gp,
                       float* __restrict__ out, int G){
    __shared__ float ssum[256], smax[256];
    int g = blockIdx.x;
    int tid = threadIdx.x;
    int c = tid & 63, sub = tid >> 6;
    int beg = gp[g], end = gp[g + 1];
    float s = 0.f, mx = -1e30f;
    for (int i = beg + sub; i < end; i += 4){
        float v = x[(long)i * 64 + c];
        s += v; mx = fmaxf(mx, v);
    }
    ssum[tid] = s; smax[tid] = mx;
    __syncthreads();
    if (tid < 64){
        for (int k = 1; k < 4; ++k){ s += ssum[tid + 64 * k]; mx = fmaxf(mx, smax[tid + 64 * k]); }
        int cnt = end - beg;
        out[g * 128 + c]      = (cnt > 0) ? s / (float)cnt : 0.f;
        out[g * 128 + 64 + c] = (cnt > 0) ? mx : 0.f;
    }
}

extern "C" void kernel_launch(void* const* d_in, const int* in_sizes, int n_in,
                              void* d_out, int out_size, void* d_ws, size_t ws_size,
                              hipStream_t stream){
    const float* x   = (const float*)d_in[0];
    const int*   ei  = (const int*)d_in[1];
    const int*   bat = (const int*)d_in[2];
    const float* W1  = (const float*)d_in[3];
    const float* a1s = (const float*)d_in[4];
    const float* a1d = (const float*)d_in[5];
    const float* b1  = (const float*)d_in[6];
    const float* g1  = (const float*)d_in[7];
    const float* be1 = (const float*)d_in[8];
    const float* W2  = (const float*)d_in[9];
    const float* a2s = (const float*)d_in[10];
    const float* a2d = (const float*)d_in[11];
    const float* b2  = (const float*)d_in[12];
    const float* g2  = (const float*)d_in[13];
    const float* be2 = (const float*)d_in[14];
    const float* W3  = (const float*)d_in[15];
    const float* a3s = (const float*)d_in[16];
    const float* a3d = (const float*)d_in[17];
    const float* b3  = (const float*)d_in[18];
    float* out = (float*)d_out;

    int N  = in_sizes[2];        // 50000
    int E0 = in_sizes[1] / 2;    // 600000
    int E  = E0 + N;             // + self-loops
    const int G = 64;
    int P  = (N + 255) / 256;    // scan blocks (196 for N=50000, must be <= 256)

    char* ws = (char*)d_ws;
    size_t off = 0;
    auto alloc = [&](size_t bytes) -> char* {
        char* p = ws + off;
        off += (bytes + 255) & ~(size_t)255;
        return p;
    };
    // --- zero-init region (one memset covers all of these) ---
    int*   counts  = (int*)alloc((size_t)N * 4);
    int*   cursor  = (int*)alloc((size_t)N * 4);
    float* sums1   = (float*)alloc(128 * 4);
    float* sumsq1  = (float*)alloc(128 * 4);
    float* sums2   = (float*)alloc(128 * 4);
    float* sumsq2  = (float*)alloc(128 * 4);
    size_t zero_bytes = off;
    // --- rest ---
    int*   part    = (int*)alloc(256 * 4);
    int*   row_ptr = (int*)alloc((size_t)(N + 1) * 4);
    int*   csr     = (int*)alloc((size_t)E * 4);
    int*   gp      = (int*)alloc((size_t)(G + 1) * 4);
    float* as_buf  = (float*)alloc((size_t)N * 4 * 4);
    float* ad_buf  = (float*)alloc((size_t)N * 4 * 4);
    float* coefs   = (float*)alloc(128 * 4);
    float* coefb   = (float*)alloc(128 * 4);
    float* hbuf    = (float*)alloc((size_t)N * 128 * 4);
    float* xcur    = (float*)alloc((size_t)N * 128 * 4);

    hipMemsetAsync(ws, 0, zero_bytes, stream);
    k_count<<<(E + 255) / 256, 256, 0, stream>>>(ei, E0, N, counts);
    k_scan_part<<<P, 256, 0, stream>>>(counts, N, part);
    k_scan_top<<<1, 256, 0, stream>>>(part, P, N, row_ptr);
    k_scan_write<<<P, 256, 0, stream>>>(counts, part, N, row_ptr);
    k_scatter<<<(E + 255) / 256, 256, 0, stream>>>(ei, E0, N, row_ptr, cursor, csr);
    k_graph_ptr<<<(N + 255) / 256, 256, 0, stream>>>(bat, N, G, gp);

    // layer 1: 5 -> 128 (4 heads); BN folded into gemm2 staging
    k_gemm1<<<2048, 256, 0, stream>>>(x, W1, a1s, a1d, hbuf, as_buf, ad_buf, N);
    k_agg<128, 4, 0><<<N, 64, 0, stream>>>(hbuf, as_buf, ad_buf, row_ptr, csr, b1, xcur, N);
    k_bn_stats<<<512, 256, 0, stream>>>(xcur, N, sums1, sumsq1);
    k_bn_coef<<<1, 128, 0, stream>>>(sums1, sumsq1, g1, be1, 1.f / N, coefs, coefb);

    // layer 2: 128 -> 128 (4 heads), BN1+ELU fused into X staging
    k_gemm_rt<128, 4, true><<<(N + 31) / 32, 256, 0, stream>>>(
        xcur, W2, a2s, a2d, coefs, coefb, hbuf, as_buf, ad_buf, N);
    k_agg<128, 4, 0><<<N, 64, 0, stream>>>(hbuf, as_buf, ad_buf, row_ptr, csr, b2, xcur, N);
    k_bn_stats<<<512, 256, 0, stream>>>(xcur, N, sums2, sumsq2);
    k_bn_coef<<<1, 128, 0, stream>>>(sums2, sumsq2, g2, be2, 1.f / N, coefs, coefb);

    // layer 3: 128 -> 64 (1 head), BN2+ELU fused into X staging, ELU fused in agg
    k_gemm_rt<64, 1, true><<<(N + 63) / 64, 256, 0, stream>>>(
        xcur, W3, a3s, a3d, coefs, coefb, hbuf, as_buf, ad_buf, N);
    k_agg<64, 1, 1><<<N, 64, 0, stream>>>(hbuf, as_buf, ad_buf, row_ptr, csr, b3, xcur, N);

    // pooling
    k_pool<<<G, 256, 0, stream>>>(xcur, gp, out, G);
}

// Round 5
// 420.001 us; speedup vs baseline: 1.4966x; 1.0262x over previous
//
#include <hip/hip_runtime.h>
#include <math.h>

#define NEG_SLOPE 0.2f
#define BN_EPS 1e-5f

__device__ __forceinline__ float lrelu_f(float x){ return x > 0.f ? x : NEG_SLOPE * x; }
__device__ __forceinline__ float elu_f(float x){ return x > 0.f ? x : __expf(x) - 1.f; }

// ordered-uint encoding for float atomicMax (monotone wrt float order, 0 < any real value's code)
__device__ __forceinline__ unsigned enc_f(float x){
    unsigned b = __float_as_uint(x);
    return (b & 0x80000000u) ? ~b : (b | 0x80000000u);
}
__device__ __forceinline__ float dec_f(unsigned u){
    return __uint_as_float((u & 0x80000000u) ? (u & 0x7FFFFFFFu) : ~u);
}

// ---------- CSR build ----------
__global__ void k_count(const int* __restrict__ ei, int E0, int N, int* __restrict__ counts){
    int i = blockIdx.x * blockDim.x + threadIdx.x;
    int tot = E0 + N;
    if (i >= tot) return;
    int dst = (i < E0) ? ei[E0 + i] : (i - E0);   // self-loops appended
    atomicAdd(&counts[dst], 1);
}

// ---------- parallel 3-phase exclusive scan over counts[n] -> row_ptr[n+1] ----------
__global__ void k_scan_part(const int* __restrict__ counts, int n, int* __restrict__ part){
    __shared__ int sh[256];
    int tid = threadIdx.x;
    int i = blockIdx.x * 256 + tid;
    int v = (i < n) ? counts[i] : 0;
    sh[tid] = v;
    __syncthreads();
    for (int o = 128; o > 0; o >>= 1){
        if (tid < o) sh[tid] += sh[tid + o];
        __syncthreads();
    }
    if (tid == 0) part[blockIdx.x] = sh[0];
}

__global__ void k_scan_top(int* __restrict__ part, int P, int n, int* __restrict__ row_ptr){
    __shared__ int sh[256];
    int tid = threadIdx.x;
    int v = (tid < P) ? part[tid] : 0;
    sh[tid] = v;
    __syncthreads();
    for (int o = 1; o < 256; o <<= 1){
        int t = (tid >= o) ? sh[tid - o] : 0;
        __syncthreads();
        sh[tid] += t;
        __syncthreads();
    }
    if (tid < P) part[tid] = sh[tid] - v;       // exclusive block offsets
    if (tid == 0) row_ptr[n] = sh[255];         // total = E
}

__global__ void k_scan_write(const int* __restrict__ counts, const int* __restrict__ part,
                             int n, int* __restrict__ row_ptr){
    __shared__ int sh[256];
    int tid = threadIdx.x;
    int i = blockIdx.x * 256 + tid;
    int v = (i < n) ? counts[i] : 0;
    sh[tid] = v;
    __syncthreads();
    for (int o = 1; o < 256; o <<= 1){
        int t = (tid >= o) ? sh[tid - o] : 0;
        __syncthreads();
        sh[tid] += t;
        __syncthreads();
    }
    if (i < n) row_ptr[i] = part[blockIdx.x] + sh[tid] - v;
}

__global__ void k_scatter(const int* __restrict__ ei, int E0, int N,
                          const int* __restrict__ row_ptr, int* __restrict__ cursor,
                          int* __restrict__ csr_src){
    int i = blockIdx.x * blockDim.x + threadIdx.x;
    int tot = E0 + N;
    if (i >= tot) return;
    int src, dst;
    if (i < E0){ src = ei[i]; dst = ei[E0 + i]; } else { src = dst = i - E0; }
    int pos = atomicAdd(&cursor[dst], 1);
    csr_src[row_ptr[dst] + pos] = src;
}

__global__ void k_graph_ptr(const int* __restrict__ batch, int N, int G, int* __restrict__ gp){
    int i = blockIdx.x * blockDim.x + threadIdx.x;
    if (i >= N) return;
    int b = batch[i];
    if (i == 0){ for (int g = 0; g <= b; ++g) gp[g] = 0; }
    else { int pb = batch[i - 1]; for (int g = pb + 1; g <= b; ++g) gp[g] = i; }
    if (i == N - 1){ for (int g = b + 1; g <= G; ++g) gp[g] = N; }
}

// ---------- layer 1 GEMM (IN=5 -> OUT=128, H=4) + attention dots ----------
__global__ void k_gemm1(const float* __restrict__ X, const float* __restrict__ W,
                        const float* __restrict__ atts, const float* __restrict__ attd,
                        float* __restrict__ h, float* __restrict__ as_, float* __restrict__ ad_,
                        int N){
    __shared__ float Wl[5 * 128];
    int tid = threadIdx.x;
    for (int i = tid; i < 5 * 128; i += 256) Wl[i] = W[i];
    __syncthreads();
    int c = tid & 127, local = tid >> 7;
    float as_c = atts[c], ad_c = attd[c];
    for (long node = (long)blockIdx.x * 2 + local; node < N; node += (long)gridDim.x * 2){
        float x0 = X[node * 5 + 0], x1 = X[node * 5 + 1], x2 = X[node * 5 + 2],
              x3 = X[node * 5 + 3], x4 = X[node * 5 + 4];
        float acc = x0 * Wl[c] + x1 * Wl[128 + c] + x2 * Wl[256 + c] +
                    x3 * Wl[384 + c] + x4 * Wl[512 + c];
        float vs = acc * as_c, vd = acc * ad_c;
#pragma unroll
        for (int m = 1; m < 32; m <<= 1){ vs += __shfl_xor(vs, m); vd += __shfl_xor(vd, m); }
        h[node * 128 + c] = acc;
        if ((c & 31) == 0){ as_[node * 4 + (c >> 5)] = vs; ad_[node * 4 + (c >> 5)] = vd; }
    }
}

// ---------- register-tiled GEMM (IN=128 -> OUT, H heads), optional fused BN+ELU on input ----------
template<int OUT, int H, bool BN>
__launch_bounds__(256)
__global__ void k_gemm_rt(const float* __restrict__ X, const float* __restrict__ W,
                          const float* __restrict__ atts, const float* __restrict__ attd,
                          const float* __restrict__ coefs, const float* __restrict__ coefb,
                          float* __restrict__ h, float* __restrict__ as_, float* __restrict__ ad_,
                          int N){
    constexpr int NCX = OUT / 4;        // threads along cols (32 or 16)
    constexpr int NNY = 256 / NCX;      // node groups (8 or 16)
    constexpr int TN  = NNY * 4;        // node tile (32 or 64)
    constexpr int KK  = 32;             // K chunk
    constexpr int XST = TN + 4;         // padded XT row stride
    __shared__ __align__(16) float Wl[KK * OUT];
    __shared__ __align__(16) float XT[KK * XST];
    int tid = threadIdx.x;
    int cx = tid % NCX, ny = tid / NCX;
    long base = (long)blockIdx.x * TN;
    float a_s[4], a_d[4];
#pragma unroll
    for (int j = 0; j < 4; ++j){ a_s[j] = atts[4 * cx + j]; a_d[j] = attd[4 * cx + j]; }
    float acc[4][4];
#pragma unroll
    for (int i = 0; i < 4; ++i)
#pragma unroll
        for (int j = 0; j < 4; ++j) acc[i][j] = 0.f;

    for (int kk = 0; kk < 128; kk += KK){
        __syncthreads();
        for (int i = tid; i < KK * OUT; i += 256) Wl[i] = W[kk * OUT + i];
        for (int i = tid; i < TN * KK; i += 256){
            int n = i >> 5, r = i & 31;
            long nn = base + n;
            float v = 0.f;
            if (nn < N){
                v = X[nn * 128 + kk + r];
                if (BN) v = elu_f(fmaf(v, coefs[kk + r], coefb[kk + r]));
            }
            XT[r * XST + n] = v;
        }
        __syncthreads();
#pragma unroll
        for (int k = 0; k < KK; ++k){
            const float4 xv = *(const float4*)&XT[k * XST + 4 * ny];
            const float4 wv = *(const float4*)&Wl[k * OUT + 4 * cx];
            acc[0][0] += xv.x * wv.x; acc[0][1] += xv.x * wv.y; acc[0][2] += xv.x * wv.z; acc[0][3] += xv.x * wv.w;
            acc[1][0] += xv.y * wv.x; acc[1][1] += xv.y * wv.y; acc[1][2] += xv.y * wv.z; acc[1][3] += xv.y * wv.w;
            acc[2][0] += xv.z * wv.x; acc[2][1] += xv.z * wv.y; acc[2][2] += xv.z * wv.z; acc[2][3] += xv.z * wv.w;
            acc[3][0] += xv.w * wv.x; acc[3][1] += xv.w * wv.y; acc[3][2] += xv.w * wv.z; acc[3][3] += xv.w * wv.w;
        }
    }
    long n0 = base + 4 * ny;
#pragma unroll
    for (int i = 0; i < 4; ++i){
        long n = n0 + i;
        if (n < N){
            float4 o; o.x = acc[i][0]; o.y = acc[i][1]; o.z = acc[i][2]; o.w = acc[i][3];
            *(float4*)&h[n * OUT + 4 * cx] = o;
        }
    }
    float ps[4], pd[4];
#pragma unroll
    for (int i = 0; i < 4; ++i){
        ps[i] = acc[i][0] * a_s[0] + acc[i][1] * a_s[1] + acc[i][2] * a_s[2] + acc[i][3] * a_s[3];
        pd[i] = acc[i][0] * a_d[0] + acc[i][1] * a_d[1] + acc[i][2] * a_d[2] + acc[i][3] * a_d[3];
    }
    constexpr int RED = NCX / H;   // lanes per head; cx == lane % NCX so xor<RED stays in-head
#pragma unroll
    for (int m = 1; m < RED; m <<= 1){
#pragma unroll
        for (int i = 0; i < 4; ++i){ ps[i] += __shfl_xor(ps[i], m); pd[i] += __shfl_xor(pd[i], m); }
    }
    if (cx % RED == 0){
        int hh = cx / RED;
#pragma unroll
        for (int i = 0; i < 4; ++i){
            long n = n0 + i;
            if (n < N){ as_[n * H + hh] = ps[i]; ad_[n * H + hh] = pd[i]; }
        }
    }
}

// ---------- GAT aggregation: one wave per destination node, single pass (no max shift) ----------
template<int C, int H, int ACT>   // ACT: 0 = none, 1 = ELU
__global__ void k_agg(const float* __restrict__ h, const float* __restrict__ as_,
                      const float* __restrict__ ad_, const int* __restrict__ row_ptr,
                      const int* __restrict__ csr_src, const float* __restrict__ bias,
                      float* __restrict__ out, int N){
    constexpr int CPL = C / 64;         // channels per lane
    constexpr int GROUP = C / H;
    int n = blockIdx.x;
    if (n >= N) return;
    int lane = threadIdx.x;
    int hh = (CPL * lane) / GROUP;
    float ad = ad_[n * H + hh];
    int beg = row_ptr[n], end = row_ptr[n + 1];
    float accx = 0.f, accy = 0.f, dn = 0.f;
    for (int e = beg; e < end; ++e){
        int s = csr_src[e];
        float l = lrelu_f(as_[s * H + hh] + ad);
        float p = __expf(l);
        dn += p;
        if (CPL == 2){
            float2 hv = *(const float2*)&h[(long)s * C + 2 * lane];
            accx += p * hv.x; accy += p * hv.y;
        } else {
            accx += p * h[(long)s * C + lane];
        }
    }
    float inv = 1.f / dn;
    if (CPL == 2){
        float vx = accx * inv + bias[2 * lane];
        float vy = accy * inv + bias[2 * lane + 1];
        if (ACT == 1){ vx = elu_f(vx); vy = elu_f(vy); }
        float2 o; o.x = vx; o.y = vy;
        *(float2*)&out[(long)n * C + 2 * lane] = o;
    } else {
        float v = accx * inv + bias[lane];
        if (ACT == 1) v = elu_f(v);
        out[(long)n * C + lane] = v;
    }
}

// ---------- BatchNorm stats, coef computed by last-done block ----------
__global__ void k_bn_stats(const float* __restrict__ x, int N,
                           float* __restrict__ sums, float* __restrict__ sumsq,
                           int* __restrict__ ticket,
                           const float* __restrict__ g, const float* __restrict__ be,
                           float invN, float* __restrict__ cs, float* __restrict__ cb){
    __shared__ float s1[256], s2[256];
    __shared__ int lastdone;
    int tid = threadIdx.x;
    int c = tid & 127, half = tid >> 7;
    float s = 0.f, q = 0.f;
    for (long i = (long)blockIdx.x * 2 + half; i < N; i += (long)gridDim.x * 2){
        float v = x[i * 128 + c]; s += v; q += v * v;
    }
    s1[tid] = s; s2[tid] = q;
    __syncthreads();
    if (tid < 128){
        s += s1[tid + 128]; q += s2[tid + 128];
        atomicAdd(&sums[c], s); atomicAdd(&sumsq[c], q);
    }
    __threadfence();
    if (tid == 0) lastdone = atomicAdd(ticket, 1);
    __syncthreads();
    if (lastdone == gridDim.x - 1 && tid < 128){
        // coherent read-back of the fully-accumulated sums (bypass possibly-stale L1)
        float su = atomicAdd(&sums[tid], 0.f);
        float sq = atomicAdd(&sumsq[tid], 0.f);
        float mu = su * invN;
        float var = sq * invN - mu * mu;
        float sc = g[tid] * rsqrtf(var + BN_EPS);
        cs[tid] = sc;
        cb[tid] = be[tid] - mu * sc;
    }
}

// ---------- pooling: stage 1 (parallel partials + atomics), stage 2 (finalize) ----------
__global__ void k_pool_part(const float* __restrict__ x, const int* __restrict__ gp,
                            float* __restrict__ psum, unsigned* __restrict__ pmax){
    constexpr int S = 16;
    __shared__ float ssum[256], smax[256];
    int g = blockIdx.y;
    int split = blockIdx.x;
    int tid = threadIdx.x;
    int c = tid & 63, sub = tid >> 6;
    int beg = gp[g], end = gp[g + 1];
    int len = end - beg;
    int chunk = (len + S - 1) / S;
    int lo = beg + split * chunk;
    int hi = lo + chunk; if (hi > end) hi = end;
    if (lo >= hi) return;
    float s = 0.f, mx = -1e30f;
    for (int i = lo + sub; i < hi; i += 4){
        float v = x[(long)i * 64 + c];
        s += v; mx = fmaxf(mx, v);
    }
    ssum[tid] = s; smax[tid] = mx;
    __syncthreads();
    if (tid < 64){
        for (int k = 1; k < 4; ++k){ s += ssum[tid + 64 * k]; mx = fmaxf(mx, smax[tid + 64 * k]); }
        atomicAdd(&psum[g * 64 + c], s);
        atomicMax(&pmax[g * 64 + c], enc_f(mx));
    }
}

__global__ void k_pool_fin(const float* __restrict__ psum, const unsigned* __restrict__ pmax,
                           const int* __restrict__ gp, float* __restrict__ out){
    int g = blockIdx.x;
    int c = threadIdx.x;   // 64 threads
    int cnt = gp[g + 1] - gp[g];
    float mean = (cnt > 0) ? psum[g * 64 + c] / (float)cnt : 0.f;
    float mx   = (cnt > 0) ? dec_f(pmax[g * 64 + c]) : 0.f;
    out[g * 128 + c]      = mean;
    out[g * 128 + 64 + c] = mx;
}

extern "C" void kernel_launch(void* const* d_in, const int* in_sizes, int n_in,
                              void* d_out, int out_size, void* d_ws, size_t ws_size,
                              hipStream_t stream){
    const float* x   = (const float*)d_in[0];
    const int*   ei  = (const int*)d_in[1];
    const int*   bat = (const int*)d_in[2];
    const float* W1  = (const float*)d_in[3];
    const float* a1s = (const float*)d_in[4];
    const float* a1d = (const float*)d_in[5];
    const float* b1  = (const float*)d_in[6];
    const float* g1  = (const float*)d_in[7];
    const float* be1 = (const float*)d_in[8];
    const float* W2  = (const float*)d_in[9];
    const float* a2s = (const float*)d_in[10];
    const float* a2d = (const float*)d_in[11];
    const float* b2  = (const float*)d_in[12];
    const float* g2  = (const float*)d_in[13];
    const float* be2 = (const float*)d_in[14];
    const float* W3  = (const float*)d_in[15];
    const float* a3s = (const float*)d_in[16];
    const float* a3d = (const float*)d_in[17];
    const float* b3  = (const float*)d_in[18];
    float* out = (float*)d_out;

    int N  = in_sizes[2];        // 50000
    int E0 = in_sizes[1] / 2;    // 600000
    int E  = E0 + N;             // + self-loops
    const int G = 64;
    int P  = (N + 255) / 256;    // scan blocks (196 for N=50000, must be <= 256)

    char* ws = (char*)d_ws;
    size_t off = 0;
    auto alloc = [&](size_t bytes) -> char* {
        char* p = ws + off;
        off += (bytes + 255) & ~(size_t)255;
        return p;
    };
    // --- zero-init region (one memset covers all of these) ---
    int*      counts  = (int*)alloc((size_t)N * 4);
    int*      cursor  = (int*)alloc((size_t)N * 4);
    float*    sums1   = (float*)alloc(128 * 4);
    float*    sumsq1  = (float*)alloc(128 * 4);
    float*    sums2   = (float*)alloc(128 * 4);
    float*    sumsq2  = (float*)alloc(128 * 4);
    int*      tick1   = (int*)alloc(4);
    int*      tick2   = (int*)alloc(4);
    float*    psum    = (float*)alloc((size_t)G * 64 * 4);
    unsigned* pmax    = (unsigned*)alloc((size_t)G * 64 * 4);
    size_t zero_bytes = off;
    // --- rest ---
    int*   part    = (int*)alloc(256 * 4);
    int*   row_ptr = (int*)alloc((size_t)(N + 1) * 4);
    int*   csr     = (int*)alloc((size_t)E * 4);
    int*   gp      = (int*)alloc((size_t)(G + 1) * 4);
    float* as_buf  = (float*)alloc((size_t)N * 4 * 4);
    float* ad_buf  = (float*)alloc((size_t)N * 4 * 4);
    float* coefs   = (float*)alloc(128 * 4);
    float* coefb   = (float*)alloc(128 * 4);
    float* hbuf    = (float*)alloc((size_t)N * 128 * 4);
    float* xcur    = (float*)alloc((size_t)N * 128 * 4);

    hipMemsetAsync(ws, 0, zero_bytes, stream);
    k_count<<<(E + 255) / 256, 256, 0, stream>>>(ei, E0, N, counts);
    k_scan_part<<<P, 256, 0, stream>>>(counts, N, part);
    k_scan_top<<<1, 256, 0, stream>>>(part, P, N, row_ptr);
    k_scan_write<<<P, 256, 0, stream>>>(counts, part, N, row_ptr);
    k_scatter<<<(E + 255) / 256, 256, 0, stream>>>(ei, E0, N, row_ptr, cursor, csr);
    k_graph_ptr<<<(N + 255) / 256, 256, 0, stream>>>(bat, N, G, gp);

    // layer 1: 5 -> 128 (4 heads); BN folded into gemm2 staging
    k_gemm1<<<2048, 256, 0, stream>>>(x, W1, a1s, a1d, hbuf, as_buf, ad_buf, N);
    k_agg<128, 4, 0><<<N, 64, 0, stream>>>(hbuf, as_buf, ad_buf, row_ptr, csr, b1, xcur, N);
    k_bn_stats<<<512, 256, 0, stream>>>(xcur, N, sums1, sumsq1, tick1, g1, be1, 1.f / N, coefs, coefb);

    // layer 2: 128 -> 128 (4 heads), BN1+ELU fused into X staging
    k_gemm_rt<128, 4, true><<<(N + 31) / 32, 256, 0, stream>>>(
        xcur, W2, a2s, a2d, coefs, coefb, hbuf, as_buf, ad_buf, N);
    k_agg<128, 4, 0><<<N, 64, 0, stream>>>(hbuf, as_buf, ad_buf, row_ptr, csr, b2, xcur, N);
    k_bn_stats<<<512, 256, 0, stream>>>(xcur, N, sums2, sumsq2, tick2, g2, be2, 1.f / N, coefs, coefb);

    // layer 3: 128 -> 64 (1 head), BN2+ELU fused into X staging, ELU fused in agg
    k_gemm_rt<64, 1, true><<<(N + 63) / 64, 256, 0, stream>>>(
        xcur, W3, a3s, a3d, coefs, coefb, hbuf, as_buf, ad_buf, N);
    k_agg<64, 1, 1><<<N, 64, 0, stream>>>(hbuf, as_buf, ad_buf, row_ptr, csr, b3, xcur, N);

    // pooling (two-stage parallel)
    {
        dim3 grid(16, G);
        k_pool_part<<<grid, 256, 0, stream>>>(xcur, gp, psum, pmax);
        k_pool_fin<<<G, 64, 0, stream>>>(psum, pmax, gp, out);
    }
}

// Round 6
// 362.390 us; speedup vs baseline: 1.7345x; 1.1590x over previous
//
#include <hip/hip_runtime.h>
#include <math.h>

#define NEG_SLOPE 0.2f
#define BN_EPS 1e-5f

__device__ __forceinline__ float lrelu_f(float x){ return x > 0.f ? x : NEG_SLOPE * x; }
__device__ __forceinline__ float elu_f(float x){ return x > 0.f ? x : __expf(x) - 1.f; }

// float -> bf16 (round-to-nearest-even), and unpack helpers
__device__ __forceinline__ unsigned short f2bf(float f){
    unsigned u = __float_as_uint(f);
    return (unsigned short)((u + 0x7fffu + ((u >> 16) & 1u)) >> 16);
}
__device__ __forceinline__ float bf_lo(unsigned v){ return __uint_as_float(v << 16); }
__device__ __forceinline__ float bf_hi(unsigned v){ return __uint_as_float(v & 0xffff0000u); }
__device__ __forceinline__ float bf2f(unsigned short b){ return __uint_as_float((unsigned)b << 16); }

// ordered-uint encoding for float atomicMax (monotone wrt float order, 0 < any real value's code)
__device__ __forceinline__ unsigned enc_f(float x){
    unsigned b = __float_as_uint(x);
    return (b & 0x80000000u) ? ~b : (b | 0x80000000u);
}
__device__ __forceinline__ float dec_f(unsigned u){
    return __uint_as_float((u & 0x80000000u) ? (u & 0x7FFFFFFFu) : ~u);
}

// ---------- CSR build ----------
__global__ void k_count(const int* __restrict__ ei, int E0, int N, int* __restrict__ counts){
    int i = blockIdx.x * blockDim.x + threadIdx.x;
    int tot = E0 + N;
    if (i >= tot) return;
    int dst = (i < E0) ? ei[E0 + i] : (i - E0);   // self-loops appended
    atomicAdd(&counts[dst], 1);
}

// ---------- parallel 3-phase exclusive scan over counts[n] -> row_ptr[n+1] ----------
__global__ void k_scan_part(const int* __restrict__ counts, int n, int* __restrict__ part){
    __shared__ int sh[256];
    int tid = threadIdx.x;
    int i = blockIdx.x * 256 + tid;
    int v = (i < n) ? counts[i] : 0;
    sh[tid] = v;
    __syncthreads();
    for (int o = 128; o > 0; o >>= 1){
        if (tid < o) sh[tid] += sh[tid + o];
        __syncthreads();
    }
    if (tid == 0) part[blockIdx.x] = sh[0];
}

__global__ void k_scan_top(int* __restrict__ part, int P, int n, int* __restrict__ row_ptr){
    __shared__ int sh[256];
    int tid = threadIdx.x;
    int v = (tid < P) ? part[tid] : 0;
    sh[tid] = v;
    __syncthreads();
    for (int o = 1; o < 256; o <<= 1){
        int t = (tid >= o) ? sh[tid - o] : 0;
        __syncthreads();
        sh[tid] += t;
        __syncthreads();
    }
    if (tid < P) part[tid] = sh[tid] - v;       // exclusive block offsets
    if (tid == 0) row_ptr[n] = sh[255];         // total = E
}

__global__ void k_scan_write(const int* __restrict__ counts, const int* __restrict__ part,
                             int n, int* __restrict__ row_ptr){
    __shared__ int sh[256];
    int tid = threadIdx.x;
    int i = blockIdx.x * 256 + tid;
    int v = (i < n) ? counts[i] : 0;
    sh[tid] = v;
    __syncthreads();
    for (int o = 1; o < 256; o <<= 1){
        int t = (tid >= o) ? sh[tid - o] : 0;
        __syncthreads();
        sh[tid] += t;
        __syncthreads();
    }
    if (i < n) row_ptr[i] = part[blockIdx.x] + sh[tid] - v;
}

__global__ void k_scatter(const int* __restrict__ ei, int E0, int N,
                          const int* __restrict__ row_ptr, int* __restrict__ cursor,
                          int* __restrict__ csr_src){
    int i = blockIdx.x * blockDim.x + threadIdx.x;
    int tot = E0 + N;
    if (i >= tot) return;
    int src, dst;
    if (i < E0){ src = ei[i]; dst = ei[E0 + i]; } else { src = dst = i - E0; }
    int pos = atomicAdd(&cursor[dst], 1);
    csr_src[row_ptr[dst] + pos] = src;
}

__global__ void k_graph_ptr(const int* __restrict__ batch, int N, int G, int* __restrict__ gp){
    int i = blockIdx.x * blockDim.x + threadIdx.x;
    if (i >= N) return;
    int b = batch[i];
    if (i == 0){ for (int g = 0; g <= b; ++g) gp[g] = 0; }
    else { int pb = batch[i - 1]; for (int g = pb + 1; g <= b; ++g) gp[g] = i; }
    if (i == N - 1){ for (int g = b + 1; g <= G; ++g) gp[g] = N; }
}

// ---------- layer 1 GEMM (IN=5 -> OUT=128, H=4) + attention dots; h stored bf16 ----------
__global__ void k_gemm1(const float* __restrict__ X, const float* __restrict__ W,
                        const float* __restrict__ atts, const float* __restrict__ attd,
                        unsigned short* __restrict__ h, float* __restrict__ as_,
                        float* __restrict__ ad_, int N){
    __shared__ float Wl[5 * 128];
    int tid = threadIdx.x;
    for (int i = tid; i < 5 * 128; i += 256) Wl[i] = W[i];
    __syncthreads();
    int c = tid & 127, local = tid >> 7;
    float as_c = atts[c], ad_c = attd[c];
    for (long node = (long)blockIdx.x * 2 + local; node < N; node += (long)gridDim.x * 2){
        float x0 = X[node * 5 + 0], x1 = X[node * 5 + 1], x2 = X[node * 5 + 2],
              x3 = X[node * 5 + 3], x4 = X[node * 5 + 4];
        float acc = x0 * Wl[c] + x1 * Wl[128 + c] + x2 * Wl[256 + c] +
                    x3 * Wl[384 + c] + x4 * Wl[512 + c];
        float vs = acc * as_c, vd = acc * ad_c;
#pragma unroll
        for (int m = 1; m < 32; m <<= 1){ vs += __shfl_xor(vs, m); vd += __shfl_xor(vd, m); }
        h[node * 128 + c] = f2bf(acc);
        if ((c & 31) == 0){ as_[node * 4 + (c >> 5)] = vs; ad_[node * 4 + (c >> 5)] = vd; }
    }
}

// ---------- register-tiled GEMM (IN=128 -> OUT, H heads), fused BN+ELU on input; h bf16 ----------
template<int OUT, int H, bool BN>
__launch_bounds__(256)
__global__ void k_gemm_rt(const float* __restrict__ X, const float* __restrict__ W,
                          const float* __restrict__ atts, const float* __restrict__ attd,
                          const float* __restrict__ coefs, const float* __restrict__ coefb,
                          unsigned short* __restrict__ h, float* __restrict__ as_,
                          float* __restrict__ ad_, int N){
    constexpr int NCX = OUT / 4;        // threads along cols (32 or 16)
    constexpr int NNY = 256 / NCX;      // node groups (8 or 16)
    constexpr int TN  = NNY * 4;        // node tile (32 or 64)
    constexpr int KK  = 32;             // K chunk
    constexpr int XST = TN + 4;         // padded XT row stride
    __shared__ __align__(16) float Wl[KK * OUT];
    __shared__ __align__(16) float XT[KK * XST];
    int tid = threadIdx.x;
    int cx = tid % NCX, ny = tid / NCX;
    long base = (long)blockIdx.x * TN;
    float a_s[4], a_d[4];
#pragma unroll
    for (int j = 0; j < 4; ++j){ a_s[j] = atts[4 * cx + j]; a_d[j] = attd[4 * cx + j]; }
    float acc[4][4];
#pragma unroll
    for (int i = 0; i < 4; ++i)
#pragma unroll
        for (int j = 0; j < 4; ++j) acc[i][j] = 0.f;

    for (int kk = 0; kk < 128; kk += KK){
        __syncthreads();
        for (int i = tid; i < KK * OUT; i += 256) Wl[i] = W[kk * OUT + i];
        for (int i = tid; i < TN * KK; i += 256){
            int n = i >> 5, r = i & 31;
            long nn = base + n;
            float v = 0.f;
            if (nn < N){
                v = X[nn * 128 + kk + r];
                if (BN) v = elu_f(fmaf(v, coefs[kk + r], coefb[kk + r]));
            }
            XT[r * XST + n] = v;
        }
        __syncthreads();
#pragma unroll
        for (int k = 0; k < KK; ++k){
            const float4 xv = *(const float4*)&XT[k * XST + 4 * ny];
            const float4 wv = *(const float4*)&Wl[k * OUT + 4 * cx];
            acc[0][0] += xv.x * wv.x; acc[0][1] += xv.x * wv.y; acc[0][2] += xv.x * wv.z; acc[0][3] += xv.x * wv.w;
            acc[1][0] += xv.y * wv.x; acc[1][1] += xv.y * wv.y; acc[1][2] += xv.y * wv.z; acc[1][3] += xv.y * wv.w;
            acc[2][0] += xv.z * wv.x; acc[2][1] += xv.z * wv.y; acc[2][2] += xv.z * wv.z; acc[2][3] += xv.z * wv.w;
            acc[3][0] += xv.w * wv.x; acc[3][1] += xv.w * wv.y; acc[3][2] += xv.w * wv.z; acc[3][3] += xv.w * wv.w;
        }
    }
    long n0 = base + 4 * ny;
#pragma unroll
    for (int i = 0; i < 4; ++i){
        long n = n0 + i;
        if (n < N){
            uint2 o;
            o.x = (unsigned)f2bf(acc[i][0]) | ((unsigned)f2bf(acc[i][1]) << 16);
            o.y = (unsigned)f2bf(acc[i][2]) | ((unsigned)f2bf(acc[i][3]) << 16);
            *(uint2*)&h[n * OUT + 4 * cx] = o;
        }
    }
    float ps[4], pd[4];
#pragma unroll
    for (int i = 0; i < 4; ++i){
        ps[i] = acc[i][0] * a_s[0] + acc[i][1] * a_s[1] + acc[i][2] * a_s[2] + acc[i][3] * a_s[3];
        pd[i] = acc[i][0] * a_d[0] + acc[i][1] * a_d[1] + acc[i][2] * a_d[2] + acc[i][3] * a_d[3];
    }
    constexpr int RED = NCX / H;   // lanes per head; cx == lane % NCX so xor<RED stays in-head
#pragma unroll
    for (int m = 1; m < RED; m <<= 1){
#pragma unroll
        for (int i = 0; i < 4; ++i){ ps[i] += __shfl_xor(ps[i], m); pd[i] += __shfl_xor(pd[i], m); }
    }
    if (cx % RED == 0){
        int hh = cx / RED;
#pragma unroll
        for (int i = 0; i < 4; ++i){
            long n = n0 + i;
            if (n < N){ as_[n * H + hh] = ps[i]; ad_[n * H + hh] = pd[i]; }
        }
    }
}

// ---------- GAT aggregation: one wave per destination node, bf16 h gather, 2x unroll ----------
template<int C, int H, int ACT>   // ACT: 0 = none, 1 = ELU
__global__ void k_agg(const unsigned short* __restrict__ h, const float* __restrict__ as_,
                      const float* __restrict__ ad_, const int* __restrict__ row_ptr,
                      const int* __restrict__ csr_src, const float* __restrict__ bias,
                      float* __restrict__ out, int N){
    constexpr int CPL = C / 64;         // channels per lane (2 for C=128, 1 for C=64)
    constexpr int GROUP = C / H;
    int n = blockIdx.x;
    if (n >= N) return;
    int lane = threadIdx.x;
    int hh = (CPL * lane) / GROUP;
    float ad = ad_[n * H + hh];
    int beg = row_ptr[n], end = row_ptr[n + 1];
    float accx = 0.f, accy = 0.f, dn = 0.f;
    const unsigned* h32 = (const unsigned*)h;
    int e = beg;
    for (; e + 2 <= end; e += 2){
        int s0 = csr_src[e], s1 = csr_src[e + 1];
        float a0 = as_[s0 * H + hh], a1 = as_[s1 * H + hh];
        unsigned v0, v1; unsigned short w0, w1;
        if (CPL == 2){ v0 = h32[(long)s0 * 64 + lane]; v1 = h32[(long)s1 * 64 + lane]; }
        else { w0 = h[(long)s0 * 64 + lane]; w1 = h[(long)s1 * 64 + lane]; }
        float p0 = __expf(lrelu_f(a0 + ad));
        float p1 = __expf(lrelu_f(a1 + ad));
        dn += p0 + p1;
        if (CPL == 2){
            accx += p0 * bf_lo(v0) + p1 * bf_lo(v1);
            accy += p0 * bf_hi(v0) + p1 * bf_hi(v1);
        } else {
            accx += p0 * bf2f(w0) + p1 * bf2f(w1);
        }
    }
    if (e < end){
        int s0 = csr_src[e];
        float p0 = __expf(lrelu_f(as_[s0 * H + hh] + ad));
        dn += p0;
        if (CPL == 2){
            unsigned v0 = h32[(long)s0 * 64 + lane];
            accx += p0 * bf_lo(v0); accy += p0 * bf_hi(v0);
        } else {
            accx += p0 * bf2f(h[(long)s0 * 64 + lane]);
        }
    }
    float inv = 1.f / dn;
    if (CPL == 2){
        float vx = accx * inv + bias[2 * lane];
        float vy = accy * inv + bias[2 * lane + 1];
        if (ACT == 1){ vx = elu_f(vx); vy = elu_f(vy); }
        float2 o; o.x = vx; o.y = vy;
        *(float2*)&out[(long)n * C + 2 * lane] = o;
    } else {
        float v = accx * inv + bias[lane];
        if (ACT == 1) v = elu_f(v);
        out[(long)n * C + lane] = v;
    }
}

// ---------- BatchNorm stats, coef computed by last-done block ----------
__global__ void k_bn_stats(const float* __restrict__ x, int N,
                           float* __restrict__ sums, float* __restrict__ sumsq,
                           int* __restrict__ ticket,
                           const float* __restrict__ g, const float* __restrict__ be,
                           float invN, float* __restrict__ cs, float* __restrict__ cb){
    __shared__ float s1[256], s2[256];
    __shared__ int lastdone;
    int tid = threadIdx.x;
    int c = tid & 127, half = tid >> 7;
    float s = 0.f, q = 0.f;
    for (long i = (long)blockIdx.x * 2 + half; i < N; i += (long)gridDim.x * 2){
        float v = x[i * 128 + c]; s += v; q += v * v;
    }
    s1[tid] = s; s2[tid] = q;
    __syncthreads();
    if (tid < 128){
        s += s1[tid + 128]; q += s2[tid + 128];
        atomicAdd(&sums[c], s); atomicAdd(&sumsq[c], q);
    }
    __threadfence();
    if (tid == 0) lastdone = atomicAdd(ticket, 1);
    __syncthreads();
    if (lastdone == gridDim.x - 1 && tid < 128){
        float su = atomicAdd(&sums[tid], 0.f);
        float sq = atomicAdd(&sumsq[tid], 0.f);
        float mu = su * invN;
        float var = sq * invN - mu * mu;
        float sc = g[tid] * rsqrtf(var + BN_EPS);
        cs[tid] = sc;
        cb[tid] = be[tid] - mu * sc;
    }
}

// ---------- pooling: stage 1 (parallel partials + atomics), stage 2 (finalize) ----------
__global__ void k_pool_part(const float* __restrict__ x, const int* __restrict__ gp,
                            float* __restrict__ psum, unsigned* __restrict__ pmax){
    constexpr int S = 16;
    __shared__ float ssum[256], smax[256];
    int g = blockIdx.y;
    int split = blockIdx.x;
    int tid = threadIdx.x;
    int c = tid & 63, sub = tid >> 6;
    int beg = gp[g], end = gp[g + 1];
    int len = end - beg;
    int chunk = (len + S - 1) / S;
    int lo = beg + split * chunk;
    int hi = lo + chunk; if (hi > end) hi = end;
    if (lo >= hi) return;
    float s = 0.f, mx = -1e30f;
    for (int i = lo + sub; i < hi; i += 4){
        float v = x[(long)i * 64 + c];
        s += v; mx = fmaxf(mx, v);
    }
    ssum[tid] = s; smax[tid] = mx;
    __syncthreads();
    if (tid < 64){
        for (int k = 1; k < 4; ++k){ s += ssum[tid + 64 * k]; mx = fmaxf(mx, smax[tid + 64 * k]); }
        atomicAdd(&psum[g * 64 + c], s);
        atomicMax(&pmax[g * 64 + c], enc_f(mx));
    }
}

__global__ void k_pool_fin(const float* __restrict__ psum, const unsigned* __restrict__ pmax,
                           const int* __restrict__ gp, float* __restrict__ out){
    int g = blockIdx.x;
    int c = threadIdx.x;   // 64 threads
    int cnt = gp[g + 1] - gp[g];
    float mean = (cnt > 0) ? psum[g * 64 + c] / (float)cnt : 0.f;
    float mx   = (cnt > 0) ? dec_f(pmax[g * 64 + c]) : 0.f;
    out[g * 128 + c]      = mean;
    out[g * 128 + 64 + c] = mx;
}

extern "C" void kernel_launch(void* const* d_in, const int* in_sizes, int n_in,
                              void* d_out, int out_size, void* d_ws, size_t ws_size,
                              hipStream_t stream){
    const float* x   = (const float*)d_in[0];
    const int*   ei  = (const int*)d_in[1];
    const int*   bat = (const int*)d_in[2];
    const float* W1  = (const float*)d_in[3];
    const float* a1s = (const float*)d_in[4];
    const float* a1d = (const float*)d_in[5];
    const float* b1  = (const float*)d_in[6];
    const float* g1  = (const float*)d_in[7];
    const float* be1 = (const float*)d_in[8];
    const float* W2  = (const float*)d_in[9];
    const float* a2s = (const float*)d_in[10];
    const float* a2d = (const float*)d_in[11];
    const float* b2  = (const float*)d_in[12];
    const float* g2  = (const float*)d_in[13];
    const float* be2 = (const float*)d_in[14];
    const float* W3  = (const float*)d_in[15];
    const float* a3s = (const float*)d_in[16];
    const float* a3d = (const float*)d_in[17];
    const float* b3  = (const float*)d_in[18];
    float* out = (float*)d_out;

    int N  = in_sizes[2];        // 50000
    int E0 = in_sizes[1] / 2;    // 600000
    int E  = E0 + N;             // + self-loops
    const int G = 64;
    int P  = (N + 255) / 256;    // scan blocks (196 for N=50000, must be <= 256)

    char* ws = (char*)d_ws;
    size_t off = 0;
    auto alloc = [&](size_t bytes) -> char* {
        char* p = ws + off;
        off += (bytes + 255) & ~(size_t)255;
        return p;
    };
    // --- zero-init region (one memset covers all of these) ---
    int*      counts  = (int*)alloc((size_t)N * 4);
    int*      cursor  = (int*)alloc((size_t)N * 4);
    float*    sums1   = (float*)alloc(128 * 4);
    float*    sumsq1  = (float*)alloc(128 * 4);
    float*    sums2   = (float*)alloc(128 * 4);
    float*    sumsq2  = (float*)alloc(128 * 4);
    int*      tick1   = (int*)alloc(4);
    int*      tick2   = (int*)alloc(4);
    float*    psum    = (float*)alloc((size_t)G * 64 * 4);
    unsigned* pmax    = (unsigned*)alloc((size_t)G * 64 * 4);
    size_t zero_bytes = off;
    // --- rest ---
    int*   part    = (int*)alloc(256 * 4);
    int*   row_ptr = (int*)alloc((size_t)(N + 1) * 4);
    int*   csr     = (int*)alloc((size_t)E * 4);
    int*   gp      = (int*)alloc((size_t)(G + 1) * 4);
    float* as_buf  = (float*)alloc((size_t)N * 4 * 4);
    float* ad_buf  = (float*)alloc((size_t)N * 4 * 4);
    float* coefs   = (float*)alloc(128 * 4);
    float* coefb   = (float*)alloc(128 * 4);
    unsigned short* hbuf = (unsigned short*)alloc((size_t)N * 128 * 2);
    float* xcur    = (float*)alloc((size_t)N * 128 * 4);

    hipMemsetAsync(ws, 0, zero_bytes, stream);
    k_count<<<(E + 255) / 256, 256, 0, stream>>>(ei, E0, N, counts);
    k_scan_part<<<P, 256, 0, stream>>>(counts, N, part);
    k_scan_top<<<1, 256, 0, stream>>>(part, P, N, row_ptr);
    k_scan_write<<<P, 256, 0, stream>>>(counts, part, N, row_ptr);
    k_scatter<<<(E + 255) / 256, 256, 0, stream>>>(ei, E0, N, row_ptr, cursor, csr);
    k_graph_ptr<<<(N + 255) / 256, 256, 0, stream>>>(bat, N, G, gp);

    // layer 1: 5 -> 128 (4 heads); BN folded into gemm2 staging
    k_gemm1<<<2048, 256, 0, stream>>>(x, W1, a1s, a1d, hbuf, as_buf, ad_buf, N);
    k_agg<128, 4, 0><<<N, 64, 0, stream>>>(hbuf, as_buf, ad_buf, row_ptr, csr, b1, xcur, N);
    k_bn_stats<<<512, 256, 0, stream>>>(xcur, N, sums1, sumsq1, tick1, g1, be1, 1.f / N, coefs, coefb);

    // layer 2: 128 -> 128 (4 heads), BN1+ELU fused into X staging
    k_gemm_rt<128, 4, true><<<(N + 31) / 32, 256, 0, stream>>>(
        xcur, W2, a2s, a2d, coefs, coefb, hbuf, as_buf, ad_buf, N);
    k_agg<128, 4, 0><<<N, 64, 0, stream>>>(hbuf, as_buf, ad_buf, row_ptr, csr, b2, xcur, N);
    k_bn_stats<<<512, 256, 0, stream>>>(xcur, N, sums2, sumsq2, tick2, g2, be2, 1.f / N, coefs, coefb);

    // layer 3: 128 -> 64 (1 head), BN2+ELU fused into X staging, ELU fused in agg
    k_gemm_rt<64, 1, true><<<(N + 63) / 64, 256, 0, stream>>>(
        xcur, W3, a3s, a3d, coefs, coefb, hbuf, as_buf, ad_buf, N);
    k_agg<64, 1, 1><<<N, 64, 0, stream>>>(hbuf, as_buf, ad_buf, row_ptr, csr, b3, xcur, N);

    // pooling (two-stage parallel)
    {
        dim3 grid(16, G);
        k_pool_part<<<grid, 256, 0, stream>>>(xcur, gp, psum, pmax);
        k_pool_fin<<<G, 64, 0, stream>>>(psum, pmax, gp, out);
    }
}

// Round 7
// 325.036 us; speedup vs baseline: 1.9339x; 1.1149x over previous
//
#include <hip/hip_runtime.h>
#include <math.h>

#define NEG_SLOPE 0.2f
#define BN_EPS 1e-5f

typedef __attribute__((ext_vector_type(8))) short short8;     // 8 bf16 (4 VGPRs), per guide
typedef __attribute__((ext_vector_type(4))) float f32x4;

__device__ __forceinline__ float lrelu_f(float x){ return x > 0.f ? x : NEG_SLOPE * x; }
__device__ __forceinline__ float elu_f(float x){ return x > 0.f ? x : __expf(x) - 1.f; }

// float -> bf16 (round-to-nearest-even), and unpack helpers
__device__ __forceinline__ unsigned short f2bf(float f){
    unsigned u = __float_as_uint(f);
    return (unsigned short)((u + 0x7fffu + ((u >> 16) & 1u)) >> 16);
}
__device__ __forceinline__ float bf_lo(unsigned v){ return __uint_as_float(v << 16); }
__device__ __forceinline__ float bf_hi(unsigned v){ return __uint_as_float(v & 0xffff0000u); }
__device__ __forceinline__ float bf2f(unsigned short b){ return __uint_as_float((unsigned)b << 16); }

// ordered-uint encoding for float atomicMax
__device__ __forceinline__ unsigned enc_f(float x){
    unsigned b = __float_as_uint(x);
    return (b & 0x80000000u) ? ~b : (b | 0x80000000u);
}
__device__ __forceinline__ float dec_f(unsigned u){
    return __uint_as_float((u & 0x80000000u) ? (u & 0x7FFFFFFFu) : ~u);
}

// ---------- CSR build ----------
__global__ void k_count(const int* __restrict__ ei, int E0, int N, int* __restrict__ counts){
    int i = blockIdx.x * blockDim.x + threadIdx.x;
    int tot = E0 + N;
    if (i >= tot) return;
    int dst = (i < E0) ? ei[E0 + i] : (i - E0);
    atomicAdd(&counts[dst], 1);
}

__global__ void k_scan_part(const int* __restrict__ counts, int n, int* __restrict__ part){
    __shared__ int sh[256];
    int tid = threadIdx.x;
    int i = blockIdx.x * 256 + tid;
    int v = (i < n) ? counts[i] : 0;
    sh[tid] = v;
    __syncthreads();
    for (int o = 128; o > 0; o >>= 1){
        if (tid < o) sh[tid] += sh[tid + o];
        __syncthreads();
    }
    if (tid == 0) part[blockIdx.x] = sh[0];
}

__global__ void k_scan_top(int* __restrict__ part, int P, int n, int* __restrict__ row_ptr){
    __shared__ int sh[256];
    int tid = threadIdx.x;
    int v = (tid < P) ? part[tid] : 0;
    sh[tid] = v;
    __syncthreads();
    for (int o = 1; o < 256; o <<= 1){
        int t = (tid >= o) ? sh[tid - o] : 0;
        __syncthreads();
        sh[tid] += t;
        __syncthreads();
    }
    if (tid < P) part[tid] = sh[tid] - v;
    if (tid == 0) row_ptr[n] = sh[255];
}

__global__ void k_scan_write(const int* __restrict__ counts, const int* __restrict__ part,
                             int n, int* __restrict__ row_ptr){
    __shared__ int sh[256];
    int tid = threadIdx.x;
    int i = blockIdx.x * 256 + tid;
    int v = (i < n) ? counts[i] : 0;
    sh[tid] = v;
    __syncthreads();
    for (int o = 1; o < 256; o <<= 1){
        int t = (tid >= o) ? sh[tid - o] : 0;
        __syncthreads();
        sh[tid] += t;
        __syncthreads();
    }
    if (i < n) row_ptr[i] = part[blockIdx.x] + sh[tid] - v;
}

__global__ void k_scatter(const int* __restrict__ ei, int E0, int N,
                          const int* __restrict__ row_ptr, int* __restrict__ cursor,
                          int* __restrict__ csr_src){
    int i = blockIdx.x * blockDim.x + threadIdx.x;
    int tot = E0 + N;
    if (i >= tot) return;
    int src, dst;
    if (i < E0){ src = ei[i]; dst = ei[E0 + i]; } else { src = dst = i - E0; }
    int pos = atomicAdd(&cursor[dst], 1);
    csr_src[row_ptr[dst] + pos] = src;
}

__global__ void k_graph_ptr(const int* __restrict__ batch, int N, int G, int* __restrict__ gp){
    int i = blockIdx.x * blockDim.x + threadIdx.x;
    if (i >= N) return;
    int b = batch[i];
    if (i == 0){ for (int g = 0; g <= b; ++g) gp[g] = 0; }
    else { int pb = batch[i - 1]; for (int g = pb + 1; g <= b; ++g) gp[g] = i; }
    if (i == N - 1){ for (int g = b + 1; g <= G; ++g) gp[g] = N; }
}

// ---------- W prep: fp32 [128][OUT] -> bf16 transposed [OUT][128] ----------
__global__ void k_wprep(const float* __restrict__ W, int OUT, unsigned short* __restrict__ Wt){
    int i = blockIdx.x * 256 + threadIdx.x;   // over 128*OUT
    if (i >= 128 * OUT) return;
    int k = i / OUT, c = i % OUT;
    Wt[c * 128 + k] = f2bf(W[i]);
}

// ---------- layer 1 GEMM (IN=5 -> OUT=128, H=4) + attention dots; h stored bf16 ----------
__global__ void k_gemm1(const float* __restrict__ X, const float* __restrict__ W,
                        const float* __restrict__ atts, const float* __restrict__ attd,
                        unsigned short* __restrict__ h, float* __restrict__ as_,
                        float* __restrict__ ad_, int N){
    __shared__ float Wl[5 * 128];
    int tid = threadIdx.x;
    for (int i = tid; i < 5 * 128; i += 256) Wl[i] = W[i];
    __syncthreads();
    int c = tid & 127, local = tid >> 7;
    float as_c = atts[c], ad_c = attd[c];
    for (long node = (long)blockIdx.x * 2 + local; node < N; node += (long)gridDim.x * 2){
        float x0 = X[node * 5 + 0], x1 = X[node * 5 + 1], x2 = X[node * 5 + 2],
              x3 = X[node * 5 + 3], x4 = X[node * 5 + 4];
        float acc = x0 * Wl[c] + x1 * Wl[128 + c] + x2 * Wl[256 + c] +
                    x3 * Wl[384 + c] + x4 * Wl[512 + c];
        float vs = acc * as_c, vd = acc * ad_c;
#pragma unroll
        for (int m = 1; m < 32; m <<= 1){ vs += __shfl_xor(vs, m); vd += __shfl_xor(vd, m); }
        h[node * 128 + c] = f2bf(acc);
        if ((c & 31) == 0){ as_[node * 4 + (c >> 5)] = vs; ad_[node * 4 + (c >> 5)] = vd; }
    }
}

// ---------- MFMA GEMM (IN=128 -> OUT, H heads), fused BN+ELU on X, bf16 in, fp32 acc ----------
// LDS layouts: row-major [rows][128] bf16, XOR-swizzled at 16B-granule level:
//   byte = row*256 + (g ^ (row&7))*16, g = k-granule (8 bf16). 2-way conflicts only (free).
template<int OUT, int H, bool BN>
__launch_bounds__(256)
__global__ void k_gemm_mfma(const float* __restrict__ X, const unsigned short* __restrict__ Wt,
                            const float* __restrict__ atts, const float* __restrict__ attd,
                            const float* __restrict__ coefs, const float* __restrict__ coefb,
                            unsigned short* __restrict__ h, float* __restrict__ as_,
                            float* __restrict__ ad_, int N){
    constexpr int TM  = 64;          // node tile (4 waves x 16)
    constexpr int NCT = OUT / 16;    // col tiles per wave (8 or 4)
    constexpr int CPH = NCT / H;     // col-tiles per head
    __shared__ unsigned short Xl[TM * 128];    // 16 KB
    __shared__ unsigned short Wl[OUT * 128];   // 32/16 KB
    int tid = threadIdx.x;
    long base = (long)blockIdx.x * TM;

    // stage Wt (bf16, already [col][k]) with swizzle
    for (int i = tid; i < OUT * 16; i += 256){
        int r = i >> 4, g = i & 15;
        uint4 v = *(const uint4*)&Wt[r * 128 + g * 8];
        int gs = g ^ (r & 7);
        *(uint4*)&Wl[r * 128 + gs * 8] = v;
    }
    // stage X rows (BN+ELU in fp32, then bf16) with swizzle
    for (int i = tid; i < TM * 16; i += 256){
        int r = i >> 4, g = i & 15;
        long node = base + r;
        uint4 o;
        if (node < N){
            const float* xp = &X[node * 128 + g * 8];
            float f[8];
            *(float4*)&f[0] = *(const float4*)xp;
            *(float4*)&f[4] = *(const float4*)(xp + 4);
#pragma unroll
            for (int j = 0; j < 8; ++j){
                float v = f[j];
                if (BN) v = elu_f(fmaf(v, coefs[g * 8 + j], coefb[g * 8 + j]));
                f[j] = v;
            }
            o.x = (unsigned)f2bf(f[0]) | ((unsigned)f2bf(f[1]) << 16);
            o.y = (unsigned)f2bf(f[2]) | ((unsigned)f2bf(f[3]) << 16);
            o.z = (unsigned)f2bf(f[4]) | ((unsigned)f2bf(f[5]) << 16);
            o.w = (unsigned)f2bf(f[6]) | ((unsigned)f2bf(f[7]) << 16);
        } else {
            o.x = o.y = o.z = o.w = 0u;
        }
        int gs = g ^ (r & 7);
        *(uint4*)&Xl[r * 128 + gs * 8] = o;
    }
    __syncthreads();

    int wid = tid >> 6;
    int lane = tid & 63;
    int lr = lane & 15, lk = lane >> 4;

    // A fragments: node row = wid*16 + lr, k = ks*32 + lk*8 + j
    short8 afrag[4];
    int arow = wid * 16 + lr;
#pragma unroll
    for (int ks = 0; ks < 4; ++ks){
        int g = ks * 4 + lk;
        int gs = g ^ (arow & 7);
        afrag[ks] = *(const short8*)&Xl[arow * 128 + gs * 8];
    }
    f32x4 acc[NCT];
#pragma unroll
    for (int ct = 0; ct < NCT; ++ct) acc[ct] = (f32x4){0.f, 0.f, 0.f, 0.f};
#pragma unroll
    for (int ct = 0; ct < NCT; ++ct){
        int brow = ct * 16 + lr;
#pragma unroll
        for (int ks = 0; ks < 4; ++ks){
            int g = ks * 4 + lk;
            int gs = g ^ (brow & 7);
            short8 bfrag = *(const short8*)&Wl[brow * 128 + gs * 8];
            acc[ct] = __builtin_amdgcn_mfma_f32_16x16x32_bf16(afrag[ks], bfrag, acc[ct], 0, 0, 0);
        }
    }
    // epilogue: lane holds col = ct*16 + lr; nodes = base + wid*16 + lk*4 + j
    float ps[H][4], pd[H][4];
#pragma unroll
    for (int hh = 0; hh < H; ++hh)
#pragma unroll
        for (int j = 0; j < 4; ++j){ ps[hh][j] = 0.f; pd[hh][j] = 0.f; }
#pragma unroll
    for (int ct = 0; ct < NCT; ++ct){
        int col = ct * 16 + lr;
        int hh = ct / CPH;
        float asv = atts[col], adv = attd[col];
#pragma unroll
        for (int j = 0; j < 4; ++j){
            float v = acc[ct][j];
            long node = base + wid * 16 + lk * 4 + j;
            if (node < N) h[node * OUT + col] = f2bf(v);
            ps[hh][j] += v * asv;
            pd[hh][j] += v * adv;
        }
    }
#pragma unroll
    for (int m = 1; m < 16; m <<= 1){
#pragma unroll
        for (int hh = 0; hh < H; ++hh)
#pragma unroll
            for (int j = 0; j < 4; ++j){
                ps[hh][j] += __shfl_xor(ps[hh][j], m);
                pd[hh][j] += __shfl_xor(pd[hh][j], m);
            }
    }
    if (lr == 0){
#pragma unroll
        for (int j = 0; j < 4; ++j){
            long node = base + wid * 16 + lk * 4 + j;
            if (node < N){
#pragma unroll
                for (int hh = 0; hh < H; ++hh){
                    as_[node * H + hh] = ps[hh][j];
                    ad_[node * H + hh] = pd[hh][j];
                }
            }
        }
    }
}

// ---------- GAT aggregation: one wave per destination node, bf16 h gather, 2x unroll ----------
template<int C, int H, int ACT>
__global__ void k_agg(const unsigned short* __restrict__ h, const float* __restrict__ as_,
                      const float* __restrict__ ad_, const int* __restrict__ row_ptr,
                      const int* __restrict__ csr_src, const float* __restrict__ bias,
                      float* __restrict__ out, int N){
    constexpr int CPL = C / 64;
    constexpr int GROUP = C / H;
    int n = blockIdx.x;
    if (n >= N) return;
    int lane = threadIdx.x;
    int hh = (CPL * lane) / GROUP;
    float ad = ad_[n * H + hh];
    int beg = row_ptr[n], end = row_ptr[n + 1];
    float accx = 0.f, accy = 0.f, dn = 0.f;
    const unsigned* h32 = (const unsigned*)h;
    int e = beg;
    for (; e + 2 <= end; e += 2){
        int s0 = csr_src[e], s1 = csr_src[e + 1];
        float a0 = as_[s0 * H + hh], a1 = as_[s1 * H + hh];
        unsigned v0, v1; unsigned short w0, w1;
        if (CPL == 2){ v0 = h32[(long)s0 * 64 + lane]; v1 = h32[(long)s1 * 64 + lane]; }
        else { w0 = h[(long)s0 * 64 + lane]; w1 = h[(long)s1 * 64 + lane]; }
        float p0 = __expf(lrelu_f(a0 + ad));
        float p1 = __expf(lrelu_f(a1 + ad));
        dn += p0 + p1;
        if (CPL == 2){
            accx += p0 * bf_lo(v0) + p1 * bf_lo(v1);
            accy += p0 * bf_hi(v0) + p1 * bf_hi(v1);
        } else {
            accx += p0 * bf2f(w0) + p1 * bf2f(w1);
        }
    }
    if (e < end){
        int s0 = csr_src[e];
        float p0 = __expf(lrelu_f(as_[s0 * H + hh] + ad));
        dn += p0;
        if (CPL == 2){
            unsigned v0 = h32[(long)s0 * 64 + lane];
            accx += p0 * bf_lo(v0); accy += p0 * bf_hi(v0);
        } else {
            accx += p0 * bf2f(h[(long)s0 * 64 + lane]);
        }
    }
    float inv = 1.f / dn;
    if (CPL == 2){
        float vx = accx * inv + bias[2 * lane];
        float vy = accy * inv + bias[2 * lane + 1];
        if (ACT == 1){ vx = elu_f(vx); vy = elu_f(vy); }
        float2 o; o.x = vx; o.y = vy;
        *(float2*)&out[(long)n * C + 2 * lane] = o;
    } else {
        float v = accx * inv + bias[lane];
        if (ACT == 1) v = elu_f(v);
        out[(long)n * C + lane] = v;
    }
}

// ---------- BatchNorm stats, coef computed by last-done block ----------
__global__ void k_bn_stats(const float* __restrict__ x, int N,
                           float* __restrict__ sums, float* __restrict__ sumsq,
                           int* __restrict__ ticket,
                           const float* __restrict__ g, const float* __restrict__ be,
                           float invN, float* __restrict__ cs, float* __restrict__ cb){
    __shared__ float s1[256], s2[256];
    __shared__ int lastdone;
    int tid = threadIdx.x;
    int c = tid & 127, half = tid >> 7;
    float s = 0.f, q = 0.f;
    for (long i = (long)blockIdx.x * 2 + half; i < N; i += (long)gridDim.x * 2){
        float v = x[i * 128 + c]; s += v; q += v * v;
    }
    s1[tid] = s; s2[tid] = q;
    __syncthreads();
    if (tid < 128){
        s += s1[tid + 128]; q += s2[tid + 128];
        atomicAdd(&sums[c], s); atomicAdd(&sumsq[c], q);
    }
    __threadfence();
    if (tid == 0) lastdone = atomicAdd(ticket, 1);
    __syncthreads();
    if (lastdone == gridDim.x - 1 && tid < 128){
        float su = atomicAdd(&sums[tid], 0.f);
        float sq = atomicAdd(&sumsq[tid], 0.f);
        float mu = su * invN;
        float var = sq * invN - mu * mu;
        float sc = g[tid] * rsqrtf(var + BN_EPS);
        cs[tid] = sc;
        cb[tid] = be[tid] - mu * sc;
    }
}

// ---------- pooling ----------
__global__ void k_pool_part(const float* __restrict__ x, const int* __restrict__ gp,
                            float* __restrict__ psum, unsigned* __restrict__ pmax){
    constexpr int S = 16;
    __shared__ float ssum[256], smax[256];
    int g = blockIdx.y;
    int split = blockIdx.x;
    int tid = threadIdx.x;
    int c = tid & 63, sub = tid >> 6;
    int beg = gp[g], end = gp[g + 1];
    int len = end - beg;
    int chunk = (len + S - 1) / S;
    int lo = beg + split * chunk;
    int hi = lo + chunk; if (hi > end) hi = end;
    if (lo >= hi) return;
    float s = 0.f, mx = -1e30f;
    for (int i = lo + sub; i < hi; i += 4){
        float v = x[(long)i * 64 + c];
        s += v; mx = fmaxf(mx, v);
    }
    ssum[tid] = s; smax[tid] = mx;
    __syncthreads();
    if (tid < 64){
        for (int k = 1; k < 4; ++k){ s += ssum[tid + 64 * k]; mx = fmaxf(mx, smax[tid + 64 * k]); }
        atomicAdd(&psum[g * 64 + c], s);
        atomicMax(&pmax[g * 64 + c], enc_f(mx));
    }
}

__global__ void k_pool_fin(const float* __restrict__ psum, const unsigned* __restrict__ pmax,
                           const int* __restrict__ gp, float* __restrict__ out){
    int g = blockIdx.x;
    int c = threadIdx.x;
    int cnt = gp[g + 1] - gp[g];
    float mean = (cnt > 0) ? psum[g * 64 + c] / (float)cnt : 0.f;
    float mx   = (cnt > 0) ? dec_f(pmax[g * 64 + c]) : 0.f;
    out[g * 128 + c]      = mean;
    out[g * 128 + 64 + c] = mx;
}

extern "C" void kernel_launch(void* const* d_in, const int* in_sizes, int n_in,
                              void* d_out, int out_size, void* d_ws, size_t ws_size,
                              hipStream_t stream){
    const float* x   = (const float*)d_in[0];
    const int*   ei  = (const int*)d_in[1];
    const int*   bat = (const int*)d_in[2];
    const float* W1  = (const float*)d_in[3];
    const float* a1s = (const float*)d_in[4];
    const float* a1d = (const float*)d_in[5];
    const float* b1  = (const float*)d_in[6];
    const float* g1  = (const float*)d_in[7];
    const float* be1 = (const float*)d_in[8];
    const float* W2  = (const float*)d_in[9];
    const float* a2s = (const float*)d_in[10];
    const float* a2d = (const float*)d_in[11];
    const float* b2  = (const float*)d_in[12];
    const float* g2  = (const float*)d_in[13];
    const float* be2 = (const float*)d_in[14];
    const float* W3  = (const float*)d_in[15];
    const float* a3s = (const float*)d_in[16];
    const float* a3d = (const float*)d_in[17];
    const float* b3  = (const float*)d_in[18];
    float* out = (float*)d_out;

    int N  = in_sizes[2];        // 50000
    int E0 = in_sizes[1] / 2;    // 600000
    int E  = E0 + N;
    const int G = 64;
    int P  = (N + 255) / 256;

    char* ws = (char*)d_ws;
    size_t off = 0;
    auto alloc = [&](size_t bytes) -> char* {
        char* p = ws + off;
        off += (bytes + 255) & ~(size_t)255;
        return p;
    };
    // --- zero-init region ---
    int*      counts  = (int*)alloc((size_t)N * 4);
    int*      cursor  = (int*)alloc((size_t)N * 4);
    float*    sums1   = (float*)alloc(128 * 4);
    float*    sumsq1  = (float*)alloc(128 * 4);
    float*    sums2   = (float*)alloc(128 * 4);
    float*    sumsq2  = (float*)alloc(128 * 4);
    int*      tick1   = (int*)alloc(4);
    int*      tick2   = (int*)alloc(4);
    float*    psum    = (float*)alloc((size_t)G * 64 * 4);
    unsigned* pmax    = (unsigned*)alloc((size_t)G * 64 * 4);
    size_t zero_bytes = off;
    // --- rest ---
    int*   part    = (int*)alloc(256 * 4);
    int*   row_ptr = (int*)alloc((size_t)(N + 1) * 4);
    int*   csr     = (int*)alloc((size_t)E * 4);
    int*   gp      = (int*)alloc((size_t)(G + 1) * 4);
    float* as_buf  = (float*)alloc((size_t)N * 4 * 4);
    float* ad_buf  = (float*)alloc((size_t)N * 4 * 4);
    float* coefs   = (float*)alloc(128 * 4);
    float* coefb   = (float*)alloc(128 * 4);
    unsigned short* wt2 = (unsigned short*)alloc(128 * 128 * 2);
    unsigned short* wt3 = (unsigned short*)alloc(64 * 128 * 2);
    unsigned short* hbuf = (unsigned short*)alloc((size_t)N * 128 * 2);
    float* xcur    = (float*)alloc((size_t)N * 128 * 4);

    hipMemsetAsync(ws, 0, zero_bytes, stream);
    k_wprep<<<64, 256, 0, stream>>>(W2, 128, wt2);
    k_wprep<<<32, 256, 0, stream>>>(W3, 64, wt3);
    k_count<<<(E + 255) / 256, 256, 0, stream>>>(ei, E0, N, counts);
    k_scan_part<<<P, 256, 0, stream>>>(counts, N, part);
    k_scan_top<<<1, 256, 0, stream>>>(part, P, N, row_ptr);
    k_scan_write<<<P, 256, 0, stream>>>(counts, part, N, row_ptr);
    k_scatter<<<(E + 255) / 256, 256, 0, stream>>>(ei, E0, N, row_ptr, cursor, csr);
    k_graph_ptr<<<(N + 255) / 256, 256, 0, stream>>>(bat, N, G, gp);

    // layer 1: 5 -> 128 (4 heads)
    k_gemm1<<<2048, 256, 0, stream>>>(x, W1, a1s, a1d, hbuf, as_buf, ad_buf, N);
    k_agg<128, 4, 0><<<N, 64, 0, stream>>>(hbuf, as_buf, ad_buf, row_ptr, csr, b1, xcur, N);
    k_bn_stats<<<512, 256, 0, stream>>>(xcur, N, sums1, sumsq1, tick1, g1, be1, 1.f / N, coefs, coefb);

    // layer 2: 128 -> 128 (4 heads), MFMA, BN1+ELU fused into X staging
    k_gemm_mfma<128, 4, true><<<(N + 63) / 64, 256, 0, stream>>>(
        xcur, wt2, a2s, a2d, coefs, coefb, hbuf, as_buf, ad_buf, N);
    k_agg<128, 4, 0><<<N, 64, 0, stream>>>(hbuf, as_buf, ad_buf, row_ptr, csr, b2, xcur, N);
    k_bn_stats<<<512, 256, 0, stream>>>(xcur, N, sums2, sumsq2, tick2, g2, be2, 1.f / N, coefs, coefb);

    // layer 3: 128 -> 64 (1 head), MFMA, BN2+ELU fused into X staging, ELU in agg
    k_gemm_mfma<64, 1, true><<<(N + 63) / 64, 256, 0, stream>>>(
        xcur, wt3, a3s, a3d, coefs, coefb, hbuf, as_buf, ad_buf, N);
    k_agg<64, 1, 1><<<N, 64, 0, stream>>>(hbuf, as_buf, ad_buf, row_ptr, csr, b3, xcur, N);

    // pooling
    {
        dim3 grid(16, G);
        k_pool_part<<<grid, 256, 0, stream>>>(xcur, gp, psum, pmax);
        k_pool_fin<<<G, 64, 0, stream>>>(psum, pmax, gp, out);
    }
}